// Round 16
// baseline (239.323 us; speedup 1.0000x reference)
//
#include <hip/hip_runtime.h>
#include <hip/hip_bf16.h>
#include <cstdint>
#include <cstddef>

#define AS1 __attribute__((address_space(1)))
#define AS3 __attribute__((address_space(3)))

typedef __attribute__((ext_vector_type(8))) short bf16x8;
typedef __attribute__((ext_vector_type(4))) float f32x4;

__device__ __forceinline__ void gload_lds16(const void* g, void* l) {
  __builtin_amdgcn_global_load_lds((const AS1 void*)g, (AS3 void*)l, 16, 0, 0);
}

#define MFMA_BF16(A, B, C) __builtin_amdgcn_mfma_f32_16x16x32_bf16((A), (B), (C), 0, 0, 0)

// (1/sqrt(128)) * log2(e) — folded into q at rope time; softmax runs in exp2 domain.
#define QSCALE 0.12751744f
// STATIC softmax max: q,k RMS-normalized => |q.k|_exp2 <= sqrt(128)*log2(e) = 16.32.
#define SMAX 16.5f

__device__ __forceinline__ uint32_t pk2(float a, float b) {
  uint32_t ua = (uint32_t)__builtin_bit_cast(unsigned short, __float2bfloat16(a));
  uint32_t ub = (uint32_t)__builtin_bit_cast(unsigned short, __float2bfloat16(b));
  return ua | (ub << 16);
}
__device__ __forceinline__ float b2f(unsigned short u) {
  return __builtin_bit_cast(float, (uint32_t)u << 16);
}

// sum over 8 consecutive lanes (group-aligned): DPP xor1, xor2, half-mirror
__device__ __forceinline__ float red8_sum(float v) {
  int x;
  x = __builtin_amdgcn_update_dpp(0, __builtin_bit_cast(int, v), 0xB1, 0xF, 0xF, true);
  v += __builtin_bit_cast(float, x);
  x = __builtin_amdgcn_update_dpp(0, __builtin_bit_cast(int, v), 0x4E, 0xF, 0xF, true);
  v += __builtin_bit_cast(float, x);
  x = __builtin_amdgcn_update_dpp(0, __builtin_bit_cast(int, v), 0x141, 0xF, 0xF, true);
  v += __builtin_bit_cast(float, x);
  return v;
}

// ---------------- merged prep: x cast + weight transposes in one launch ----------------
__global__ __launch_bounds__(256) void prep_kernel(const float* __restrict__ x,
                                                   __hip_bfloat16* __restrict__ xb,
                                                   const float* __restrict__ Wq,
                                                   const float* __restrict__ Wk,
                                                   const float* __restrict__ Wv,
                                                   const float* __restrict__ Wp,
                                                   __hip_bfloat16* __restrict__ WTa,
                                                   __hip_bfloat16* __restrict__ WpT) {
  __shared__ float tile[32][33];
  int id = blockIdx.x;
  int tx = threadIdx.x, ty = threadIdx.y;
  if (id < 8192) {
    int i = id * 256 + ty * 32 + tx;
    float4 v = ((const float4*)x)[i];
    __hip_bfloat16* o = xb + (size_t)i * 4;
    o[0] = __float2bfloat16(v.x);
    o[1] = __float2bfloat16(v.y);
    o[2] = __float2bfloat16(v.z);
    o[3] = __float2bfloat16(v.w);
    return;
  }
  id -= 8192;
  const float* in; __hip_bfloat16* out; int is, os, bx, by;
  if (id < 4096)      { in = Wq; out = WTa;                          is = 2048; os = 2048; bx = id & 63; by = id >> 6; }
  else if (id < 5120) { int t = id - 4096; in = Wk; out = WTa + (size_t)2048 * 2048; is = 512; os = 2048; bx = t & 15; by = t >> 4; }
  else if (id < 6144) { int t = id - 5120; in = Wv; out = WTa + (size_t)2560 * 2048; is = 512; os = 2048; bx = t & 15; by = t >> 4; }
  else                { int t = id - 6144; in = Wp; out = WpT;       is = 2048; os = 2048; bx = t & 63; by = t >> 6; }
  int c0 = bx * 32, r0 = by * 32;
#pragma unroll
  for (int i = 0; i < 32; i += 8)
    tile[ty + i][tx] = in[(size_t)(r0 + ty + i) * is + c0 + tx];
  __syncthreads();
#pragma unroll
  for (int i = 0; i < 32; i += 8)
    out[(size_t)(c0 + ty + i) * os + r0 + tx] = __float2bfloat16(tile[tx][ty + i]);
}

// ---------------- qkv GEMM: 128x128 tile, BK=64, 4 waves, 2-phase counted-vmcnt ----------------
__global__ __launch_bounds__(256, 2) void gemm_qkv_rope_kernel(
    const __hip_bfloat16* __restrict__ A,
    const __hip_bfloat16* __restrict__ Bt,
    const float* __restrict__ cosb,
    const float* __restrict__ sinb,
    __hip_bfloat16* __restrict__ qT,
    __hip_bfloat16* __restrict__ kT,
    __hip_bfloat16* __restrict__ vt) {
  __shared__ __align__(16) char smem[65536];
  __hip_bfloat16* CL4 = (__hip_bfloat16*)smem;    // elem idx = (q4*133+col)*4 + rr
  const int K = 2048;
  const int tid = threadIdx.x;
  const int lane = tid & 63;
  const int wid = tid >> 6;
  const int wm = wid >> 1, wn = wid & 1;
  const int bid = blockIdx.x;
  const int swz = (bid & 7) * 96 + (bid >> 3);
  const int tm = swz / 24, tn = swz % 24;
  const int row0 = tm << 7, col0 = tn << 7;
  const int fr = lane & 15, hi = lane >> 4;

  auto STAGE = [&](int buf, int k0) {
#pragma unroll
    for (int i = 0; i < 4; ++i) {
      int f = i * 256 + tid;
      int r = f >> 3, s = f & 7, sx = s ^ (r & 7);
      gload_lds16(A + (size_t)(row0 + r) * K + k0 + sx * 8,
                  smem + buf * 16384 + f * 16);
    }
#pragma unroll
    for (int i = 0; i < 4; ++i) {
      int f = i * 256 + tid;
      int r = f >> 3, s = f & 7, sx = s ^ (r & 7);
      gload_lds16(Bt + (size_t)(col0 + r) * K + k0 + sx * 8,
                  smem + 32768 + buf * 16384 + f * 16);
    }
  };

  f32x4 acc[4][4] = {};
  STAGE(0, 0);
  int cur = 0;
  for (int kk = 0; kk < 32; ++kk) {
    if (kk > 0) __builtin_amdgcn_s_barrier();
    __builtin_amdgcn_sched_barrier(0);
    if (kk + 1 < 32) STAGE(cur ^ 1, (kk + 1) * 64);
    __builtin_amdgcn_sched_barrier(0);
    if (kk + 1 < 32) asm volatile("s_waitcnt vmcnt(8)" ::: "memory");
    else             asm volatile("s_waitcnt vmcnt(0)" ::: "memory");
    __builtin_amdgcn_s_barrier();
    __builtin_amdgcn_sched_barrier(0);
    const char* Ac = smem + cur * 16384;
    const char* Bc = smem + 32768 + cur * 16384;
#pragma unroll
    for (int kh = 0; kh < 2; ++kh) {
      bf16x8 af[4], bfr[4];
#pragma unroll
      for (int n = 0; n < 4; ++n) {
        int rowb = wn * 64 + n * 16 + fr;
        int sl = (kh * 4 + hi) ^ (rowb & 7);
        bfr[n] = *(const bf16x8*)(Bc + rowb * 128 + sl * 16);
      }
#pragma unroll
      for (int m = 0; m < 4; ++m) {
        int rowa = wm * 64 + m * 16 + fr;
        int sl = (kh * 4 + hi) ^ (rowa & 7);
        af[m] = *(const bf16x8*)(Ac + rowa * 128 + sl * 16);
      }
      __builtin_amdgcn_s_setprio(1);
#pragma unroll
      for (int m = 0; m < 4; ++m)
#pragma unroll
        for (int n = 0; n < 4; ++n)
          acc[m][n] = MFMA_BF16(af[m], bfr[n], acc[m][n]);
      __builtin_amdgcn_s_setprio(0);
    }
    cur ^= 1;
  }
  __syncthreads();

  // ---- pack acc -> CL4 ----
#pragma unroll
  for (int m = 0; m < 4; ++m)
#pragma unroll
    for (int n = 0; n < 4; ++n) {
      int q4 = wm * 16 + m * 4 + hi;
      int col = wn * 64 + n * 16 + fr;
      *(uint2*)(CL4 + ((q4 * 133 + col) << 2)) =
          make_uint2(pk2(acc[m][n][0], acc[m][n][1]), pk2(acc[m][n][2], acc[m][n][3]));
    }
  __syncthreads();

  const int b = row0 >> 11;
  const int t0 = row0 & 2047;

  if (col0 >= 2560) {
    const int hv = (col0 - 2560) >> 7;
    __hip_bfloat16* vb = vt + (size_t)(b * 4 + hv) * 128 * 2048;
    const int col = tid >> 1, th = tid & 1;
    uint2 w[16];
#pragma unroll
    for (int qq = 0; qq < 16; ++qq)
      w[qq] = *(const uint2*)(CL4 + (((th * 16 + qq) * 133 + col) << 2));
    __hip_bfloat16* dstv = vb + (size_t)col * 2048 + t0 + th * 64;
#pragma unroll
    for (int e = 0; e < 8; ++e)
      *(uint4*)(dstv + e * 8) = make_uint4(w[2 * e].x, w[2 * e].y, w[2 * e + 1].x, w[2 * e + 1].y);
    return;
  }

  const int quad = tid >> 3, cp = tid & 7;
  const int tb = t0 + quad * 4;
  bf16x8 lov[4], hiv[4];
#pragma unroll
  for (int e = 0; e < 4; ++e) {
    lov[e] = *(const bf16x8*)(CL4 + ((quad * 133 + cp * 8 + e * 2) << 2));
    hiv[e] = *(const bf16x8*)(CL4 + ((quad * 133 + 64 + cp * 8 + e * 2) << 2));
  }
  const float oscale = (col0 < 2048) ? QSCALE : 1.0f;
  __hip_bfloat16* dstq = (col0 < 2048)
      ? qT + (size_t)(b * 16 + (col0 >> 7)) * 2048 * 128
      : kT + (size_t)(b * 4 + ((col0 - 2048) >> 7)) * 2048 * 128;

  float o1v[4][8], o2v[4][8], ssum[4];
#pragma unroll
  for (int rr = 0; rr < 4; ++rr) {
    const float* cb = cosb + (size_t)(tb + rr) * 64 + cp * 8;
    const float* sb = sinb + (size_t)(tb + rr) * 64 + cp * 8;
    float4 c0 = *(const float4*)cb, c1 = *(const float4*)(cb + 4);
    float4 s0 = *(const float4*)sb, s1 = *(const float4*)(sb + 4);
    float cc[8] = {c0.x, c0.y, c0.z, c0.w, c1.x, c1.y, c1.z, c1.w};
    float sn[8] = {s0.x, s0.y, s0.z, s0.w, s1.x, s1.y, s1.z, s1.w};
    float ss = 0.f;
#pragma unroll
    for (int e = 0; e < 4; ++e)
#pragma unroll
      for (int w2 = 0; w2 < 2; ++w2) {
        int pd = e * 2 + w2;
        float x1 = b2f((unsigned short)lov[e][w2 * 4 + rr]);
        float x2 = b2f((unsigned short)hiv[e][w2 * 4 + rr]);
        float a = x1 * cc[pd] - x2 * sn[pd];
        float bb = x1 * sn[pd] + x2 * cc[pd];
        o1v[rr][pd] = a;
        o2v[rr][pd] = bb;
        ss += a * a + bb * bb;
      }
    ssum[rr] = ss;
  }
#pragma unroll
  for (int rr = 0; rr < 4; ++rr) {
    float rn = rsqrtf(red8_sum(ssum[rr]) * (1.f / 128.f) + 1e-6f) * oscale;
    __hip_bfloat16* dr = dstq + (size_t)(tb + rr) * 128 + cp * 8;
    *(uint4*)dr = make_uint4(pk2(o1v[rr][0] * rn, o1v[rr][1] * rn),
                             pk2(o1v[rr][2] * rn, o1v[rr][3] * rn),
                             pk2(o1v[rr][4] * rn, o1v[rr][5] * rn),
                             pk2(o1v[rr][6] * rn, o1v[rr][7] * rn));
    *(uint4*)(dr + 64) = make_uint4(pk2(o2v[rr][0] * rn, o2v[rr][1] * rn),
                                    pk2(o2v[rr][2] * rn, o2v[rr][3] * rn),
                                    pk2(o2v[rr][4] * rn, o2v[rr][5] * rn),
                                    pk2(o2v[rr][6] * rn, o2v[rr][7] * rn));
  }
}

// ---------------- generic bf16 GEMM: 128x128 tile, BK=64, swizzled (f32 out) ----------------
__global__ __launch_bounds__(256, 2) void gemm_bf16_kernel(const __hip_bfloat16* __restrict__ A,
                                                           const __hip_bfloat16* __restrict__ Bt,
                                                           float* __restrict__ C,
                                                           int M, int N, int K) {
  __shared__ __align__(16) char smem[65536];
  const int tid = threadIdx.x;
  const int lane = tid & 63;
  const int wid = tid >> 6;
  const int wm = wid >> 1, wn = wid & 1;
  const int nwg = gridDim.x;
  const int bid = blockIdx.x;
  const int swz = (bid & 7) * (nwg >> 3) + (bid >> 3);
  const int ntile = N >> 7;
  const int tm = swz / ntile, tn = swz % ntile;
  const int row0 = tm << 7, col0 = tn << 7;
  const int fr = lane & 15, hi = lane >> 4;

  auto STAGE = [&](int buf, int k0) {
#pragma unroll
    for (int i = 0; i < 4; ++i) {
      int f = i * 256 + tid;
      int r = f >> 3, s = f & 7, sx = s ^ (r & 7);
      gload_lds16(A + (size_t)(row0 + r) * K + k0 + sx * 8,
                  smem + buf * 16384 + f * 16);
    }
#pragma unroll
    for (int i = 0; i < 4; ++i) {
      int f = i * 256 + tid;
      int r = f >> 3, s = f & 7, sx = s ^ (r & 7);
      gload_lds16(Bt + (size_t)(col0 + r) * K + k0 + sx * 8,
                  smem + 32768 + buf * 16384 + f * 16);
    }
  };

  f32x4 acc[4][4] = {};
  const int nk = K >> 6;
  STAGE(0, 0);
  int cur = 0;
  for (int kk = 0; kk < nk; ++kk) {
    if (kk > 0) __builtin_amdgcn_s_barrier();
    __builtin_amdgcn_sched_barrier(0);
    if (kk + 1 < nk) STAGE(cur ^ 1, (kk + 1) * 64);
    __builtin_amdgcn_sched_barrier(0);
    if (kk + 1 < nk) asm volatile("s_waitcnt vmcnt(8)" ::: "memory");
    else             asm volatile("s_waitcnt vmcnt(0)" ::: "memory");
    __builtin_amdgcn_s_barrier();
    __builtin_amdgcn_sched_barrier(0);
    const char* Ac = smem + cur * 16384;
    const char* Bc = smem + 32768 + cur * 16384;
#pragma unroll
    for (int kh = 0; kh < 2; ++kh) {
      bf16x8 af[4], bfr[4];
#pragma unroll
      for (int n = 0; n < 4; ++n) {
        int rowb = wn * 64 + n * 16 + fr;
        int sl = (kh * 4 + hi) ^ (rowb & 7);
        bfr[n] = *(const bf16x8*)(Bc + rowb * 128 + sl * 16);
      }
#pragma unroll
      for (int m = 0; m < 4; ++m) {
        int rowa = wm * 64 + m * 16 + fr;
        int sl = (kh * 4 + hi) ^ (rowa & 7);
        af[m] = *(const bf16x8*)(Ac + rowa * 128 + sl * 16);
      }
      __builtin_amdgcn_s_setprio(1);
#pragma unroll
      for (int m = 0; m < 4; ++m)
#pragma unroll
        for (int n = 0; n < 4; ++n)
          acc[m][n] = MFMA_BF16(af[m], bfr[n], acc[m][n]);
      __builtin_amdgcn_s_setprio(0);
    }
    cur ^= 1;
  }

  const int cr = hi * 4;
#pragma unroll
  for (int m = 0; m < 4; ++m)
#pragma unroll
    for (int n = 0; n < 4; ++n) {
      int col = col0 + wn * 64 + n * 16 + fr;
#pragma unroll
      for (int r = 0; r < 4; ++r) {
        int row = row0 + wm * 64 + m * 16 + cr + r;
        C[(size_t)row * N + col] = acc[m][n][r];
      }
    }
}

// MERGED-PAIR attention blocks: 256 blocks x 512 threads (8 waves), 1 block/CU.
// bi: g=bi&7 (=(b*4+kvh), XCD-local K/V), j=(bi>>3)&7, bh=g*4+((bi>>6)&3).
// Waves 0-3 own q-block j (rows ww*32..), waves 4-7 own q-block 15-j — both share
// ONE staged K/V stream of length nsteps = 32-2j (covers both causal ranges),
// halving HBM fetch + staging issue vs split blocks. LDS 96KB (K dbuf+V dbuf+8xP).
// STATIC-MAX softmax, per-lane lazy l (pass1); stored-denominator normalize (pass2).

// ---------------- attention pass 1 ----------------
__global__ __launch_bounds__(512, 2) void attn_pass1_kernel(
    const __hip_bfloat16* __restrict__ qT,   // (B,H,T,HD), q pre-scaled
    const __hip_bfloat16* __restrict__ kT,   // (B,HK,T,HD)
    const __hip_bfloat16* __restrict__ vt,   // (B,HK,HD,T)
    __hip_bfloat16* __restrict__ y1u,        // (B,H,HD,T)  u = mix1*v + mix2*y1
    float* __restrict__ Lb,                  // (B,H,T)
    const float* __restrict__ mix1p,
    const float* __restrict__ mix2p) {
  __shared__ __align__(16) __hip_bfloat16 Ks[2][64 * 128];
  __shared__ __align__(16) __hip_bfloat16 Vs[2][128 * 64];
  __shared__ __align__(16) char Ps[8][32 * 128];
  const int tid = threadIdx.x, lane = tid & 63, w = tid >> 6;   // w 0..7
  const int bi = blockIdx.x;
  const int g = bi & 7;
  const int j = (bi >> 3) & 7;
  const int bh = g * 4 + ((bi >> 6) & 3);
  const int ww = w & 3;
  const int qblk = (w < 4) ? j : (15 - j);
  const int q0 = qblk * 128;
  const int sd = 2 * qblk + (ww >> 1);       // this wave's diagonal k-tile
  const int nsteps = 32 - 2 * j;             // B-stream length >= A-stream length
  const __hip_bfloat16* Kp = kT + (size_t)g * 2048 * 128;
  const __hip_bfloat16* Vp = vt + (size_t)g * 128 * 2048;
  const int fr = lane & 15, hi = lane >> 4;

  bf16x8 qf[2][4];
  {
    const __hip_bfloat16* Qp = qT + ((size_t)bh * 2048 + q0 + ww * 32) * 128;
#pragma unroll
    for (int rr = 0; rr < 2; ++rr)
#pragma unroll
      for (int dc = 0; dc < 4; ++dc)
        qf[rr][dc] = *(const bf16x8*)(Qp + (rr * 16 + fr) * 128 + dc * 32 + hi * 8);
  }

  f32x4 accO[2][8] = {};
  float l[2] = {0.f, 0.f};
  char* Pb = Ps[w];

  auto STAGE = [&](int buf, int kt) {        // 4 loads/thread (2 K + 2 V)
    const int k0 = kt * 64;
#pragma unroll
    for (int i = 0; i < 2; ++i) {
      int f = i * 512 + tid;
      int r = f >> 4, s = f & 15, sx = s ^ (r & 7);
      gload_lds16(Kp + (size_t)(k0 + r) * 128 + sx * 8,
                  (char*)Ks[buf] + (i * 512 + w * 64) * 16);
    }
#pragma unroll
    for (int i = 0; i < 2; ++i) {
      int f = i * 512 + tid;
      int r = f >> 3, s = f & 7, sx = s ^ (r & 7);
      gload_lds16(Vp + (size_t)r * 2048 + k0 + sx * 8,
                  (char*)Vs[buf] + (i * 512 + w * 64) * 16);
    }
  };

  STAGE(0, 0);
  for (int s = 0; s < nsteps; ++s) {
    if (s > 0) __builtin_amdgcn_s_barrier();   // WAR: compute(s-1) closed
    __builtin_amdgcn_sched_barrier(0);
    if (s + 1 < nsteps) STAGE((s + 1) & 1, s + 1);
    __builtin_amdgcn_sched_barrier(0);
    if (s + 1 < nsteps) asm volatile("s_waitcnt vmcnt(4)" ::: "memory");
    else                asm volatile("s_waitcnt vmcnt(0)" ::: "memory");
    __builtin_amdgcn_s_barrier();              // K(s),V(s) landed for all waves
    __builtin_amdgcn_sched_barrier(0);

    if (s <= sd) {
      // ---- QK (swapped): sf[rr][c][r] = S[q=rr*16+fr][k=c*16+hi*4+r] ----
      const char* Kc = (const char*)Ks[s & 1];
      f32x4 sf[2][4] = {};
      __builtin_amdgcn_s_setprio(1);
#pragma unroll
      for (int c = 0; c < 4; ++c) {
        const int krow = c * 16 + fr;
#pragma unroll
        for (int dc = 0; dc < 4; ++dc) {
          int slot = (dc * 4 + hi) ^ (krow & 7);
          bf16x8 kf = *(const bf16x8*)(Kc + krow * 256 + slot * 16);
          sf[0][c] = MFMA_BF16(kf, qf[0][dc], sf[0][c]);
          sf[1][c] = MFMA_BF16(kf, qf[1][dc], sf[1][c]);
        }
      }
      __builtin_amdgcn_s_setprio(0);
      // ---- mask (diagonal only) + static-max exp2 + per-lane partial sum ----
      if (s == sd) {
#pragma unroll
        for (int rr = 0; rr < 2; ++rr) {
          const int qq = q0 + ww * 32 + rr * 16 + fr;
#pragma unroll
          for (int c = 0; c < 4; ++c) {
            const int kb = s * 64 + c * 16 + hi * 4;
#pragma unroll
            for (int r = 0; r < 4; ++r)
              if (kb + r > qq) sf[rr][c][r] = -1e30f;
          }
        }
      }
#pragma unroll
      for (int rr = 0; rr < 2; ++rr) {
        float rs = 0.f;
#pragma unroll
        for (int c = 0; c < 4; ++c)
#pragma unroll
          for (int r = 0; r < 4; ++r) {
            float p = __builtin_amdgcn_exp2f(sf[rr][c][r] - SMAX);
            sf[rr][c][r] = p;
            rs += p;
          }
        l[rr] += rs;
      }
      // ---- P -> LDS (packed b64, swizzled) + A-frag readback ----
#pragma unroll
      for (int rr = 0; rr < 2; ++rr) {
        const int row = rr * 16 + fr;
        char* Prow = Pb + row * 128;
#pragma unroll
        for (int c = 0; c < 4; ++c) {
          uint32_t w0 = pk2(sf[rr][c][0], sf[rr][c][1]);
          uint32_t w1 = pk2(sf[rr][c][2], sf[rr][c][3]);
          int sl = (c * 2 + (hi >> 1)) ^ (row & 7);
          *(uint2*)(Prow + sl * 16 + (hi & 1) * 8) = make_uint2(w0, w1);
        }
      }
      bf16x8 pf[2][2];
#pragma unroll
      for (int rr = 0; rr < 2; ++rr) {
        const int row = rr * 16 + fr;
#pragma unroll
        for (int kc = 0; kc < 2; ++kc) {
          int sl = (kc * 4 + hi) ^ (row & 7);
          pf[rr][kc] = *(const bf16x8*)(Pb + row * 128 + sl * 16);
        }
      }
      // ---- PV ----
      const __hip_bfloat16* Vc = Vs[s & 1];
      __builtin_amdgcn_s_setprio(1);
#pragma unroll
      for (int kc = 0; kc < 2; ++kc)
#pragma unroll
        for (int f = 0; f < 8; ++f) {
          int vrow = f * 16 + fr;
          int vslot = (kc * 4 + hi) ^ (fr & 7);
          bf16x8 vf = *(const bf16x8*)(Vc + vrow * 64 + vslot * 8);
          accO[0][f] = MFMA_BF16(pf[0][kc], vf, accO[0][f]);
          accO[1][f] = MFMA_BF16(pf[1][kc], vf, accO[1][f]);
        }
      __builtin_amdgcn_s_setprio(0);
    }
  }

  // ---- epilogue: reduce per-lane l; u = mix1*v + mix2*(accO/l); store l ----
  float lsum[2];
#pragma unroll
  for (int rr = 0; rr < 2; ++rr) {
    float v = l[rr];
    v += __shfl_xor(v, 16);
    v += __shfl_xor(v, 32);
    lsum[rr] = v;
  }
  const float m1v = mix1p[0], m2v = mix2p[0];
  float rlq[2][4];
#pragma unroll
  for (int rr = 0; rr < 2; ++rr) {
    float inv = 1.f / lsum[rr];
#pragma unroll
    for (int r = 0; r < 4; ++r) rlq[rr][r] = __shfl(inv, hi * 4 + r);
  }
  const int t0 = q0 + ww * 32;
#pragma unroll
  for (int rr = 0; rr < 2; ++rr) {
    const int tb = t0 + rr * 16 + hi * 4;
#pragma unroll
    for (int f = 0; f < 8; ++f) {
      const int d = f * 16 + fr;
      const ushort4 v4 = *(const ushort4*)(vt + ((size_t)g * 128 + d) * 2048 + tb);
      float u0 = m1v * b2f(v4.x) + m2v * (accO[rr][f][0] * rlq[rr][0]);
      float u1 = m1v * b2f(v4.y) + m2v * (accO[rr][f][1] * rlq[rr][1]);
      float u2 = m1v * b2f(v4.z) + m2v * (accO[rr][f][2] * rlq[rr][2]);
      float u3 = m1v * b2f(v4.w) + m2v * (accO[rr][f][3] * rlq[rr][3]);
      *(uint2*)(y1u + ((size_t)bh * 128 + d) * 2048 + tb) =
          make_uint2(pk2(u0, u1), pk2(u2, u3));
    }
  }
  if (hi == 0) {
#pragma unroll
    for (int rr = 0; rr < 2; ++rr)
      Lb[(size_t)bh * 2048 + t0 + rr * 16 + fr] = lsum[rr];
  }
}

// ---------------- attention pass 2: ymix = att @ u  (direct final output) ----------------
__global__ __launch_bounds__(512, 2) void attn_pass2_kernel(
    const __hip_bfloat16* __restrict__ qT,
    const __hip_bfloat16* __restrict__ kT,
    const __hip_bfloat16* __restrict__ y1u,  // (B,H,HD,T)
    const float* __restrict__ Lb,
    __hip_bfloat16* __restrict__ ymix) {     // (B,T,C)
  __shared__ __align__(16) __hip_bfloat16 Ks[2][64 * 128];
  __shared__ __align__(16) __hip_bfloat16 Vs[2][128 * 64];
  __shared__ __align__(16) char Ps[8][32 * 128];
  const int tid = threadIdx.x, lane = tid & 63, w = tid >> 6;
  const int bi = blockIdx.x;
  const int g = bi & 7;
  const int j = (bi >> 3) & 7;
  const int bh = g * 4 + ((bi >> 6) & 3);
  const int h = bh & 15, b = bh >> 4;
  const int ww = w & 3;
  const int qblk = (w < 4) ? j : (15 - j);
  const int q0 = qblk * 128;
  const int sd = 2 * qblk + (ww >> 1);
  const int nsteps = 32 - 2 * j;
  const __hip_bfloat16* Kp = kT + (size_t)g * 2048 * 128;
  const __hip_bfloat16* Yp = y1u + (size_t)bh * 128 * 2048;
  const int fr = lane & 15, hi = lane >> 4;

  bf16x8 qf[2][4];
  float rl[2];
  {
    const __hip_bfloat16* Qp = qT + ((size_t)bh * 2048 + q0 + ww * 32) * 128;
#pragma unroll
    for (int rr = 0; rr < 2; ++rr)
#pragma unroll
      for (int dc = 0; dc < 4; ++dc)
        qf[rr][dc] = *(const bf16x8*)(Qp + (rr * 16 + fr) * 128 + dc * 32 + hi * 8);
    const size_t qb = (size_t)bh * 2048 + q0 + ww * 32;
    rl[0] = 1.f / Lb[qb + fr];
    rl[1] = 1.f / Lb[qb + 16 + fr];
  }

  f32x4 accO[2][8] = {};
  char* Pb = Ps[w];

  auto STAGE = [&](int buf, int kt) {
    const int k0 = kt * 64;
#pragma unroll
    for (int i = 0; i < 2; ++i) {
      int f = i * 512 + tid;
      int r = f >> 4, s = f & 15, sx = s ^ (r & 7);
      gload_lds16(Kp + (size_t)(k0 + r) * 128 + sx * 8,
                  (char*)Ks[buf] + (i * 512 + w * 64) * 16);
    }
#pragma unroll
    for (int i = 0; i < 2; ++i) {
      int f = i * 512 + tid;
      int r = f >> 3, s = f & 7, sx = s ^ (r & 7);
      gload_lds16(Yp + (size_t)r * 2048 + k0 + sx * 8,
                  (char*)Vs[buf] + (i * 512 + w * 64) * 16);
    }
  };

  STAGE(0, 0);
  for (int s = 0; s < nsteps; ++s) {
    if (s > 0) __builtin_amdgcn_s_barrier();
    __builtin_amdgcn_sched_barrier(0);
    if (s + 1 < nsteps) STAGE((s + 1) & 1, s + 1);
    __builtin_amdgcn_sched_barrier(0);
    if (s + 1 < nsteps) asm volatile("s_waitcnt vmcnt(4)" ::: "memory");
    else                asm volatile("s_waitcnt vmcnt(0)" ::: "memory");
    __builtin_amdgcn_s_barrier();
    __builtin_amdgcn_sched_barrier(0);

    if (s <= sd) {
      const char* Kc = (const char*)Ks[s & 1];
      f32x4 sf[2][4] = {};
      __builtin_amdgcn_s_setprio(1);
#pragma unroll
      for (int c = 0; c < 4; ++c) {
        const int krow = c * 16 + fr;
#pragma unroll
        for (int dc = 0; dc < 4; ++dc) {
          int slot = (dc * 4 + hi) ^ (krow & 7);
          bf16x8 kf = *(const bf16x8*)(Kc + krow * 256 + slot * 16);
          sf[0][c] = MFMA_BF16(kf, qf[0][dc], sf[0][c]);
          sf[1][c] = MFMA_BF16(kf, qf[1][dc], sf[1][c]);
        }
      }
      __builtin_amdgcn_s_setprio(0);
      // normalize P with static max + stored denominator (no shuffles)
      if (s == sd) {
#pragma unroll
        for (int rr = 0; rr < 2; ++rr) {
          const int qq = q0 + ww * 32 + rr * 16 + fr;
#pragma unroll
          for (int c = 0; c < 4; ++c) {
            const int kb = s * 64 + c * 16 + hi * 4;
#pragma unroll
            for (int r = 0; r < 4; ++r)
              if (kb + r > qq) sf[rr][c][r] = -1e30f;
          }
        }
      }
#pragma unroll
      for (int rr = 0; rr < 2; ++rr)
#pragma unroll
        for (int c = 0; c < 4; ++c)
#pragma unroll
          for (int r = 0; r < 4; ++r)
            sf[rr][c][r] = __builtin_amdgcn_exp2f(sf[rr][c][r] - SMAX) * rl[rr];
#pragma unroll
      for (int rr = 0; rr < 2; ++rr) {
        const int row = rr * 16 + fr;
        char* Prow = Pb + row * 128;
#pragma unroll
        for (int c = 0; c < 4; ++c) {
          uint32_t w0 = pk2(sf[rr][c][0], sf[rr][c][1]);
          uint32_t w1 = pk2(sf[rr][c][2], sf[rr][c][3]);
          int sl = (c * 2 + (hi >> 1)) ^ (row & 7);
          *(uint2*)(Prow + sl * 16 + (hi & 1) * 8) = make_uint2(w0, w1);
        }
      }
      bf16x8 pf[2][2];
#pragma unroll
      for (int rr = 0; rr < 2; ++rr) {
        const int row = rr * 16 + fr;
#pragma unroll
        for (int kc = 0; kc < 2; ++kc) {
          int sl = (kc * 4 + hi) ^ (row & 7);
          pf[rr][kc] = *(const bf16x8*)(Pb + row * 128 + sl * 16);
        }
      }
      const __hip_bfloat16* Vc = Vs[s & 1];
      __builtin_amdgcn_s_setprio(1);
#pragma unroll
      for (int kc = 0; kc < 2; ++kc)
#pragma unroll
        for (int f = 0; f < 8; ++f) {
          int vrow = f * 16 + fr;
          int vslot = (kc * 4 + hi) ^ (fr & 7);
          bf16x8 vf = *(const bf16x8*)(Vc + vrow * 64 + vslot * 8);
          accO[0][f] = MFMA_BF16(pf[0][kc], vf, accO[0][f]);
          accO[1][f] = MFMA_BF16(pf[1][kc], vf, accO[1][f]);
        }
      __builtin_amdgcn_s_setprio(0);
    }
  }

  // accO already IS the final mixed output (P pre-normalized, u pre-mixed)
#pragma unroll
  for (int rr = 0; rr < 2; ++rr) {
#pragma unroll
    for (int f = 0; f < 8; ++f) {
      const int d = f * 16 + fr;
#pragma unroll
      for (int r = 0; r < 4; ++r) {
        int q = q0 + ww * 32 + rr * 16 + hi * 4 + r;
        ymix[((size_t)b * 2048 + q) * 2048 + h * 128 + d] = __float2bfloat16(accO[rr][f][r]);
      }
    }
  }
}

// ---------------- launch ----------------
extern "C" void kernel_launch(void* const* d_in, const int* in_sizes, int n_in,
                              void* d_out, int out_size, void* d_ws, size_t ws_size,
                              hipStream_t stream) {
  const float* x    = (const float*)d_in[0];
  const float* cosb = (const float*)d_in[1];
  const float* sinb = (const float*)d_in[2];
  const float* Wq   = (const float*)d_in[3];
  const float* Wk   = (const float*)d_in[4];
  const float* Wv   = (const float*)d_in[5];
  const float* Wp   = (const float*)d_in[6];
  const float* mix1 = (const float*)d_in[7];
  const float* mix2 = (const float*)d_in[8];
  float* out = (float*)d_out;
  char* ws = (char*)d_ws;

  // workspace layout (bytes), peak ~80 MB
  __hip_bfloat16* xb   = (__hip_bfloat16*)(ws + 0);            // 16.78 MB; reused as ymix
  __hip_bfloat16* WTa  = (__hip_bfloat16*)(ws + 16777216);     // 12.58 MB
  __hip_bfloat16* WpT  = (__hip_bfloat16*)(ws + 29360128);     // 8.39 MB
  __hip_bfloat16* y1u  = (__hip_bfloat16*)(ws + 37748736);     // 16.78 MB
  float*          Lb   = (float*)(ws + 54525952);              // 0.26 MB
  __hip_bfloat16* qTb  = (__hip_bfloat16*)(ws + 55050240);     // 16.78 MB
  __hip_bfloat16* kTb  = (__hip_bfloat16*)(ws + 71827456);     // 4.19 MB
  __hip_bfloat16* vtb  = (__hip_bfloat16*)(ws + 76021760);     // 4.19 MB
  __hip_bfloat16* ymix = (__hip_bfloat16*)(ws + 0);

  dim3 tb(32, 8);
  prep_kernel<<<18432, tb, 0, stream>>>(x, xb, Wq, Wk, Wv, Wp, WTa, WpT);

  // fused QKV projection + RoPE + RMS + V-transpose (128x128 tiles, BK=64, 768 blocks)
  gemm_qkv_rope_kernel<<<768, 256, 0, stream>>>(xb, WTa, cosb, sinb, qTb, kTb, vtb);

  attn_pass1_kernel<<<256, 512, 0, stream>>>(qTb, kTb, vtb, y1u, Lb, mix1, mix2);
  attn_pass2_kernel<<<256, 512, 0, stream>>>(qTb, kTb, y1u, Lb, ymix);

  gemm_bf16_kernel<<<512, 256, 0, stream>>>(ymix, WpT, out, 4096, 2048, 2048);
}

// Round 17
// 233.753 us; speedup vs baseline: 1.0238x; 1.0238x over previous
//
#include <hip/hip_runtime.h>
#include <hip/hip_bf16.h>
#include <cstdint>
#include <cstddef>

#define AS1 __attribute__((address_space(1)))
#define AS3 __attribute__((address_space(3)))

typedef __attribute__((ext_vector_type(8))) short bf16x8;
typedef __attribute__((ext_vector_type(4))) float f32x4;

__device__ __forceinline__ void gload_lds16(const void* g, void* l) {
  __builtin_amdgcn_global_load_lds((const AS1 void*)g, (AS3 void*)l, 16, 0, 0);
}

#define MFMA_BF16(A, B, C) __builtin_amdgcn_mfma_f32_16x16x32_bf16((A), (B), (C), 0, 0, 0)

// (1/sqrt(128)) * log2(e) — folded into q at rope time; softmax runs in exp2 domain.
#define QSCALE 0.12751744f
// STATIC softmax max: q,k RMS-normalized => |q.k|_exp2 <= sqrt(128)*log2(e) = 16.32.
// exp2(s - SMAX) <= 1 always, so online max tracking is unnecessary (exact softmax).
#define SMAX 16.5f

__device__ __forceinline__ uint32_t pk2(float a, float b) {
  uint32_t ua = (uint32_t)__builtin_bit_cast(unsigned short, __float2bfloat16(a));
  uint32_t ub = (uint32_t)__builtin_bit_cast(unsigned short, __float2bfloat16(b));
  return ua | (ub << 16);
}
__device__ __forceinline__ float b2f(unsigned short u) {
  return __builtin_bit_cast(float, (uint32_t)u << 16);
}

// sum over 8 consecutive lanes (group-aligned): DPP xor1, xor2, half-mirror
__device__ __forceinline__ float red8_sum(float v) {
  int x;
  x = __builtin_amdgcn_update_dpp(0, __builtin_bit_cast(int, v), 0xB1, 0xF, 0xF, true);
  v += __builtin_bit_cast(float, x);
  x = __builtin_amdgcn_update_dpp(0, __builtin_bit_cast(int, v), 0x4E, 0xF, 0xF, true);
  v += __builtin_bit_cast(float, x);
  x = __builtin_amdgcn_update_dpp(0, __builtin_bit_cast(int, v), 0x141, 0xF, 0xF, true);
  v += __builtin_bit_cast(float, x);
  return v;
}

// ---------------- merged prep: x cast + weight transposes in one launch ----------------
__global__ __launch_bounds__(256) void prep_kernel(const float* __restrict__ x,
                                                   __hip_bfloat16* __restrict__ xb,
                                                   const float* __restrict__ Wq,
                                                   const float* __restrict__ Wk,
                                                   const float* __restrict__ Wv,
                                                   const float* __restrict__ Wp,
                                                   __hip_bfloat16* __restrict__ WTa,
                                                   __hip_bfloat16* __restrict__ WpT) {
  __shared__ float tile[32][33];
  int id = blockIdx.x;
  int tx = threadIdx.x, ty = threadIdx.y;
  if (id < 8192) {
    int i = id * 256 + ty * 32 + tx;
    float4 v = ((const float4*)x)[i];
    __hip_bfloat16* o = xb + (size_t)i * 4;
    o[0] = __float2bfloat16(v.x);
    o[1] = __float2bfloat16(v.y);
    o[2] = __float2bfloat16(v.z);
    o[3] = __float2bfloat16(v.w);
    return;
  }
  id -= 8192;
  const float* in; __hip_bfloat16* out; int is, os, bx, by;
  if (id < 4096)      { in = Wq; out = WTa;                          is = 2048; os = 2048; bx = id & 63; by = id >> 6; }
  else if (id < 5120) { int t = id - 4096; in = Wk; out = WTa + (size_t)2048 * 2048; is = 512; os = 2048; bx = t & 15; by = t >> 4; }
  else if (id < 6144) { int t = id - 5120; in = Wv; out = WTa + (size_t)2560 * 2048; is = 512; os = 2048; bx = t & 15; by = t >> 4; }
  else                { int t = id - 6144; in = Wp; out = WpT;       is = 2048; os = 2048; bx = t & 63; by = t >> 6; }
  int c0 = bx * 32, r0 = by * 32;
#pragma unroll
  for (int i = 0; i < 32; i += 8)
    tile[ty + i][tx] = in[(size_t)(r0 + ty + i) * is + c0 + tx];
  __syncthreads();
#pragma unroll
  for (int i = 0; i < 32; i += 8)
    out[(size_t)(c0 + ty + i) * os + r0 + tx] = __float2bfloat16(tile[tx][ty + i]);
}

// ---------------- qkv GEMM: 128x128 tile, BK=64, 4 waves, 2-phase counted-vmcnt ----------------
__global__ __launch_bounds__(256, 2) void gemm_qkv_rope_kernel(
    const __hip_bfloat16* __restrict__ A,
    const __hip_bfloat16* __restrict__ Bt,
    const float* __restrict__ cosb,
    const float* __restrict__ sinb,
    __hip_bfloat16* __restrict__ qT,
    __hip_bfloat16* __restrict__ kT,
    __hip_bfloat16* __restrict__ vt) {
  __shared__ __align__(16) char smem[65536];
  __hip_bfloat16* CL4 = (__hip_bfloat16*)smem;    // elem idx = (q4*133+col)*4 + rr
  const int K = 2048;
  const int tid = threadIdx.x;
  const int lane = tid & 63;
  const int wid = tid >> 6;
  const int wm = wid >> 1, wn = wid & 1;
  const int bid = blockIdx.x;
  const int swz = (bid & 7) * 96 + (bid >> 3);
  const int tm = swz / 24, tn = swz % 24;
  const int row0 = tm << 7, col0 = tn << 7;
  const int fr = lane & 15, hi = lane >> 4;

  auto STAGE = [&](int buf, int k0) {
#pragma unroll
    for (int i = 0; i < 4; ++i) {
      int f = i * 256 + tid;
      int r = f >> 3, s = f & 7, sx = s ^ (r & 7);
      gload_lds16(A + (size_t)(row0 + r) * K + k0 + sx * 8,
                  smem + buf * 16384 + f * 16);
    }
#pragma unroll
    for (int i = 0; i < 4; ++i) {
      int f = i * 256 + tid;
      int r = f >> 3, s = f & 7, sx = s ^ (r & 7);
      gload_lds16(Bt + (size_t)(col0 + r) * K + k0 + sx * 8,
                  smem + 32768 + buf * 16384 + f * 16);
    }
  };

  f32x4 acc[4][4] = {};
  STAGE(0, 0);
  int cur = 0;
  for (int kk = 0; kk < 32; ++kk) {
    if (kk > 0) __builtin_amdgcn_s_barrier();
    __builtin_amdgcn_sched_barrier(0);
    if (kk + 1 < 32) STAGE(cur ^ 1, (kk + 1) * 64);
    __builtin_amdgcn_sched_barrier(0);
    if (kk + 1 < 32) asm volatile("s_waitcnt vmcnt(8)" ::: "memory");
    else             asm volatile("s_waitcnt vmcnt(0)" ::: "memory");
    __builtin_amdgcn_s_barrier();
    __builtin_amdgcn_sched_barrier(0);
    const char* Ac = smem + cur * 16384;
    const char* Bc = smem + 32768 + cur * 16384;
#pragma unroll
    for (int kh = 0; kh < 2; ++kh) {
      bf16x8 af[4], bfr[4];
#pragma unroll
      for (int n = 0; n < 4; ++n) {
        int rowb = wn * 64 + n * 16 + fr;
        int sl = (kh * 4 + hi) ^ (rowb & 7);
        bfr[n] = *(const bf16x8*)(Bc + rowb * 128 + sl * 16);
      }
#pragma unroll
      for (int m = 0; m < 4; ++m) {
        int rowa = wm * 64 + m * 16 + fr;
        int sl = (kh * 4 + hi) ^ (rowa & 7);
        af[m] = *(const bf16x8*)(Ac + rowa * 128 + sl * 16);
      }
      __builtin_amdgcn_s_setprio(1);
#pragma unroll
      for (int m = 0; m < 4; ++m)
#pragma unroll
        for (int n = 0; n < 4; ++n)
          acc[m][n] = MFMA_BF16(af[m], bfr[n], acc[m][n]);
      __builtin_amdgcn_s_setprio(0);
    }
    cur ^= 1;
  }
  __syncthreads();

  // ---- pack acc -> CL4 ----
#pragma unroll
  for (int m = 0; m < 4; ++m)
#pragma unroll
    for (int n = 0; n < 4; ++n) {
      int q4 = wm * 16 + m * 4 + hi;
      int col = wn * 64 + n * 16 + fr;
      *(uint2*)(CL4 + ((q4 * 133 + col) << 2)) =
          make_uint2(pk2(acc[m][n][0], acc[m][n][1]), pk2(acc[m][n][2], acc[m][n][3]));
    }
  __syncthreads();

  const int b = row0 >> 11;
  const int t0 = row0 & 2047;

  if (col0 >= 2560) {
    const int hv = (col0 - 2560) >> 7;
    __hip_bfloat16* vb = vt + (size_t)(b * 4 + hv) * 128 * 2048;
    const int col = tid >> 1, th = tid & 1;
    uint2 w[16];
#pragma unroll
    for (int qq = 0; qq < 16; ++qq)
      w[qq] = *(const uint2*)(CL4 + (((th * 16 + qq) * 133 + col) << 2));
    __hip_bfloat16* dstv = vb + (size_t)col * 2048 + t0 + th * 64;
#pragma unroll
    for (int e = 0; e < 8; ++e)
      *(uint4*)(dstv + e * 8) = make_uint4(w[2 * e].x, w[2 * e].y, w[2 * e + 1].x, w[2 * e + 1].y);
    return;
  }

  const int quad = tid >> 3, cp = tid & 7;
  const int tb = t0 + quad * 4;
  bf16x8 lov[4], hiv[4];
#pragma unroll
  for (int e = 0; e < 4; ++e) {
    lov[e] = *(const bf16x8*)(CL4 + ((quad * 133 + cp * 8 + e * 2) << 2));
    hiv[e] = *(const bf16x8*)(CL4 + ((quad * 133 + 64 + cp * 8 + e * 2) << 2));
  }
  const float oscale = (col0 < 2048) ? QSCALE : 1.0f;
  __hip_bfloat16* dstq = (col0 < 2048)
      ? qT + (size_t)(b * 16 + (col0 >> 7)) * 2048 * 128
      : kT + (size_t)(b * 4 + ((col0 - 2048) >> 7)) * 2048 * 128;

  float o1v[4][8], o2v[4][8], ssum[4];
#pragma unroll
  for (int rr = 0; rr < 4; ++rr) {
    const float* cb = cosb + (size_t)(tb + rr) * 64 + cp * 8;
    const float* sb = sinb + (size_t)(tb + rr) * 64 + cp * 8;
    float4 c0 = *(const float4*)cb, c1 = *(const float4*)(cb + 4);
    float4 s0 = *(const float4*)sb, s1 = *(const float4*)(sb + 4);
    float cc[8] = {c0.x, c0.y, c0.z, c0.w, c1.x, c1.y, c1.z, c1.w};
    float sn[8] = {s0.x, s0.y, s0.z, s0.w, s1.x, s1.y, s1.z, s1.w};
    float ss = 0.f;
#pragma unroll
    for (int e = 0; e < 4; ++e)
#pragma unroll
      for (int w2 = 0; w2 < 2; ++w2) {
        int pd = e * 2 + w2;
        float x1 = b2f((unsigned short)lov[e][w2 * 4 + rr]);
        float x2 = b2f((unsigned short)hiv[e][w2 * 4 + rr]);
        float a = x1 * cc[pd] - x2 * sn[pd];
        float bb = x1 * sn[pd] + x2 * cc[pd];
        o1v[rr][pd] = a;
        o2v[rr][pd] = bb;
        ss += a * a + bb * bb;
      }
    ssum[rr] = ss;
  }
#pragma unroll
  for (int rr = 0; rr < 4; ++rr) {
    float rn = rsqrtf(red8_sum(ssum[rr]) * (1.f / 128.f) + 1e-6f) * oscale;
    __hip_bfloat16* dr = dstq + (size_t)(tb + rr) * 128 + cp * 8;
    *(uint4*)dr = make_uint4(pk2(o1v[rr][0] * rn, o1v[rr][1] * rn),
                             pk2(o1v[rr][2] * rn, o1v[rr][3] * rn),
                             pk2(o1v[rr][4] * rn, o1v[rr][5] * rn),
                             pk2(o1v[rr][6] * rn, o1v[rr][7] * rn));
    *(uint4*)(dr + 64) = make_uint4(pk2(o2v[rr][0] * rn, o2v[rr][1] * rn),
                                    pk2(o2v[rr][2] * rn, o2v[rr][3] * rn),
                                    pk2(o2v[rr][4] * rn, o2v[rr][5] * rn),
                                    pk2(o2v[rr][6] * rn, o2v[rr][7] * rn));
  }
}

// ---------------- generic bf16 GEMM: 128x128 tile, BK=64, swizzled (f32 out) ----------------
__global__ __launch_bounds__(256, 2) void gemm_bf16_kernel(const __hip_bfloat16* __restrict__ A,
                                                           const __hip_bfloat16* __restrict__ Bt,
                                                           float* __restrict__ C,
                                                           int M, int N, int K) {
  __shared__ __align__(16) char smem[65536];
  const int tid = threadIdx.x;
  const int lane = tid & 63;
  const int wid = tid >> 6;
  const int wm = wid >> 1, wn = wid & 1;
  const int nwg = gridDim.x;
  const int bid = blockIdx.x;
  const int swz = (bid & 7) * (nwg >> 3) + (bid >> 3);
  const int ntile = N >> 7;
  const int tm = swz / ntile, tn = swz % ntile;
  const int row0 = tm << 7, col0 = tn << 7;
  const int fr = lane & 15, hi = lane >> 4;

  auto STAGE = [&](int buf, int k0) {
#pragma unroll
    for (int i = 0; i < 4; ++i) {
      int f = i * 256 + tid;
      int r = f >> 3, s = f & 7, sx = s ^ (r & 7);
      gload_lds16(A + (size_t)(row0 + r) * K + k0 + sx * 8,
                  smem + buf * 16384 + f * 16);
    }
#pragma unroll
    for (int i = 0; i < 4; ++i) {
      int f = i * 256 + tid;
      int r = f >> 3, s = f & 7, sx = s ^ (r & 7);
      gload_lds16(Bt + (size_t)(col0 + r) * K + k0 + sx * 8,
                  smem + 32768 + buf * 16384 + f * 16);
    }
  };

  f32x4 acc[4][4] = {};
  const int nk = K >> 6;
  STAGE(0, 0);
  int cur = 0;
  for (int kk = 0; kk < nk; ++kk) {
    if (kk > 0) __builtin_amdgcn_s_barrier();
    __builtin_amdgcn_sched_barrier(0);
    if (kk + 1 < nk) STAGE(cur ^ 1, (kk + 1) * 64);
    __builtin_amdgcn_sched_barrier(0);
    if (kk + 1 < nk) asm volatile("s_waitcnt vmcnt(8)" ::: "memory");
    else             asm volatile("s_waitcnt vmcnt(0)" ::: "memory");
    __builtin_amdgcn_s_barrier();
    __builtin_amdgcn_sched_barrier(0);
    const char* Ac = smem + cur * 16384;
    const char* Bc = smem + 32768 + cur * 16384;
#pragma unroll
    for (int kh = 0; kh < 2; ++kh) {
      bf16x8 af[4], bfr[4];
#pragma unroll
      for (int n = 0; n < 4; ++n) {
        int rowb = wn * 64 + n * 16 + fr;
        int sl = (kh * 4 + hi) ^ (rowb & 7);
        bfr[n] = *(const bf16x8*)(Bc + rowb * 128 + sl * 16);
      }
#pragma unroll
      for (int m = 0; m < 4; ++m) {
        int rowa = wm * 64 + m * 16 + fr;
        int sl = (kh * 4 + hi) ^ (rowa & 7);
        af[m] = *(const bf16x8*)(Ac + rowa * 128 + sl * 16);
      }
      __builtin_amdgcn_s_setprio(1);
#pragma unroll
      for (int m = 0; m < 4; ++m)
#pragma unroll
        for (int n = 0; n < 4; ++n)
          acc[m][n] = MFMA_BF16(af[m], bfr[n], acc[m][n]);
      __builtin_amdgcn_s_setprio(0);
    }
    cur ^= 1;
  }

  const int cr = hi * 4;
#pragma unroll
  for (int m = 0; m < 4; ++m)
#pragma unroll
    for (int n = 0; n < 4; ++n) {
      int col = col0 + wn * 64 + n * 16 + fr;
#pragma unroll
      for (int r = 0; r < 4; ++r) {
        int row = row0 + wm * 64 + m * 16 + cr + r;
        C[(size_t)row * N + col] = acc[m][n][r];
      }
    }
}

// block decode (both passes): bi in [0,512): u=bi&255, half=bi>>8. g=u&7 = (b*4+kvh).
// bi and bi+256 (two halves of a balanced 34-step pair) land on the same CU under rr
// dispatch: per-CU balance at 2 blocks/CU.
//
// STATIC-MAX SOFTMAX: no online max tracking (scores bounded by SMAX); P = exp2(s-SMAX),
// l accumulated per-lane, reduced once in the epilogue. Zero cross-lane ops in the loop.

// ---------------- attention pass 1: y1 = softmax(qk^T) v ; writes u = mix1*v + mix2*y1 ----------------
__global__ __launch_bounds__(256, 2) void attn_pass1_kernel(
    const __hip_bfloat16* __restrict__ qT,   // (B,H,T,HD), q pre-scaled
    const __hip_bfloat16* __restrict__ kT,   // (B,HK,T,HD)
    const __hip_bfloat16* __restrict__ vt,   // (B,HK,HD,T)
    __hip_bfloat16* __restrict__ y1u,        // (B,H,HD,T)  u = mix1*v + mix2*y1
    float* __restrict__ Lb,                  // (B,H,T)
    const float* __restrict__ mix1p,
    const float* __restrict__ mix2p) {
  __shared__ __align__(16) __hip_bfloat16 Ks[2][64 * 128];
  __shared__ __align__(16) __hip_bfloat16 Vs[2][128 * 64];
  __shared__ __align__(16) char Ps[4][32 * 128];
  const int tid = threadIdx.x, lane = tid & 63, wid = tid >> 6;   // wid 0..3
  const int bi = blockIdx.x;
  const int u = bi & 255, half = bi >> 8;
  const int g = u & 7;
  const int pslot = (u >> 3) & 7;
  const int bh = g * 4 + (u >> 6);
  const int j = half ? (15 - pslot) : pslot;
  const int q0 = j * 128;
  const int nt = 2 * j + 2;                  // even
  const int sd = 2 * j + (wid >> 1);
  const __hip_bfloat16* Kp = kT + (size_t)g * 2048 * 128;
  const __hip_bfloat16* Vp = vt + (size_t)g * 128 * 2048;
  const int fr = lane & 15, hi = lane >> 4;

  bf16x8 qf[2][4];
  {
    const __hip_bfloat16* Qp = qT + ((size_t)bh * 2048 + q0 + wid * 32) * 128;
#pragma unroll
    for (int rr = 0; rr < 2; ++rr)
#pragma unroll
      for (int dc = 0; dc < 4; ++dc)
        qf[rr][dc] = *(const bf16x8*)(Qp + (rr * 16 + fr) * 128 + dc * 32 + hi * 8);
  }

  f32x4 accO[2][8] = {};
  float l[2] = {0.f, 0.f};                   // per-lane partial denominators

  char* Pb = Ps[wid];

  auto STAGE = [&](int buf, int kt) {        // 8 global_load_lds (4 K + 4 V)
    const int k0 = kt * 64;
#pragma unroll
    for (int i = 0; i < 4; ++i) {
      int f = i * 256 + tid;
      int r = f >> 4, s = f & 15, sx = s ^ (r & 7);
      gload_lds16(Kp + (size_t)(k0 + r) * 128 + sx * 8,
                  (char*)Ks[buf] + (i * 256 + wid * 64) * 16);
    }
#pragma unroll
    for (int i = 0; i < 4; ++i) {
      int f = i * 256 + tid;
      int r = f >> 3, s = f & 7, sx = s ^ (r & 7);
      gload_lds16(Vp + (size_t)r * 2048 + k0 + sx * 8,
                  (char*)Vs[buf] + (i * 256 + wid * 64) * 16);
    }
  };

  STAGE(0, 0);
  for (int s = 0; s < nt; ++s) {
    if (s > 0) __builtin_amdgcn_s_barrier();   // WAR: compute(s-1) closed
    __builtin_amdgcn_sched_barrier(0);
    if (s + 1 < nt) STAGE((s + 1) & 1, s + 1);
    __builtin_amdgcn_sched_barrier(0);
    if (s + 1 < nt) asm volatile("s_waitcnt vmcnt(8)" ::: "memory");
    else            asm volatile("s_waitcnt vmcnt(0)" ::: "memory");
    __builtin_amdgcn_s_barrier();              // K(s),V(s) landed for all waves
    __builtin_amdgcn_sched_barrier(0);

    if (s <= sd) {
      // ---- QK (swapped): sf[rr][c][r] = S[q=rr*16+fr][k=c*16+hi*4+r] ----
      const char* Kc = (const char*)Ks[s & 1];
      f32x4 sf[2][4] = {};
      __builtin_amdgcn_s_setprio(1);
#pragma unroll
      for (int c = 0; c < 4; ++c) {
        const int krow = c * 16 + fr;
#pragma unroll
        for (int dc = 0; dc < 4; ++dc) {
          int slot = (dc * 4 + hi) ^ (krow & 7);
          bf16x8 kf = *(const bf16x8*)(Kc + krow * 256 + slot * 16);
          sf[0][c] = MFMA_BF16(kf, qf[0][dc], sf[0][c]);
          sf[1][c] = MFMA_BF16(kf, qf[1][dc], sf[1][c]);
        }
      }
      __builtin_amdgcn_s_setprio(0);
      // ---- mask (diagonal only) + static-max exp2 + per-lane partial sum ----
      if (s == sd) {
#pragma unroll
        for (int rr = 0; rr < 2; ++rr) {
          const int qq = q0 + wid * 32 + rr * 16 + fr;
#pragma unroll
          for (int c = 0; c < 4; ++c) {
            const int kb = s * 64 + c * 16 + hi * 4;
#pragma unroll
            for (int r = 0; r < 4; ++r)
              if (kb + r > qq) sf[rr][c][r] = -1e30f;
          }
        }
      }
#pragma unroll
      for (int rr = 0; rr < 2; ++rr) {
        float rs = 0.f;
#pragma unroll
        for (int c = 0; c < 4; ++c)
#pragma unroll
          for (int r = 0; r < 4; ++r) {
            float p = __builtin_amdgcn_exp2f(sf[rr][c][r] - SMAX);
            sf[rr][c][r] = p;
            rs += p;
          }
        l[rr] += rs;
      }
      // ---- P -> LDS (packed b64, swizzled) + A-frag readback ----
#pragma unroll
      for (int rr = 0; rr < 2; ++rr) {
        const int row = rr * 16 + fr;
        char* Prow = Pb + row * 128;
#pragma unroll
        for (int c = 0; c < 4; ++c) {
          uint32_t w0 = pk2(sf[rr][c][0], sf[rr][c][1]);
          uint32_t w1 = pk2(sf[rr][c][2], sf[rr][c][3]);
          int sl = (c * 2 + (hi >> 1)) ^ (row & 7);
          *(uint2*)(Prow + sl * 16 + (hi & 1) * 8) = make_uint2(w0, w1);
        }
      }
      bf16x8 pf[2][2];
#pragma unroll
      for (int rr = 0; rr < 2; ++rr) {
        const int row = rr * 16 + fr;
#pragma unroll
        for (int kc = 0; kc < 2; ++kc) {
          int sl = (kc * 4 + hi) ^ (row & 7);
          pf[rr][kc] = *(const bf16x8*)(Pb + row * 128 + sl * 16);
        }
      }
      // ---- PV ----
      const __hip_bfloat16* Vc = Vs[s & 1];
      __builtin_amdgcn_s_setprio(1);
#pragma unroll
      for (int kc = 0; kc < 2; ++kc)
#pragma unroll
        for (int f = 0; f < 8; ++f) {
          int vrow = f * 16 + fr;
          int vslot = (kc * 4 + hi) ^ (fr & 7);
          bf16x8 vf = *(const bf16x8*)(Vc + vrow * 64 + vslot * 8);
          accO[0][f] = MFMA_BF16(pf[0][kc], vf, accO[0][f]);
          accO[1][f] = MFMA_BF16(pf[1][kc], vf, accO[1][f]);
        }
      __builtin_amdgcn_s_setprio(0);
    }
  }

  // ---- epilogue: reduce per-lane l once; u = mix1*v + mix2*(accO/l); store l ----
  float lsum[2];
#pragma unroll
  for (int rr = 0; rr < 2; ++rr) {
    float v = l[rr];
    v += __shfl_xor(v, 16);
    v += __shfl_xor(v, 32);
    lsum[rr] = v;
  }
  const float m1v = mix1p[0], m2v = mix2p[0];
  float rlq[2][4];
#pragma unroll
  for (int rr = 0; rr < 2; ++rr) {
    float inv = 1.f / lsum[rr];
#pragma unroll
    for (int r = 0; r < 4; ++r) rlq[rr][r] = __shfl(inv, hi * 4 + r);
  }
  const int t0 = q0 + wid * 32;
#pragma unroll
  for (int rr = 0; rr < 2; ++rr) {
    const int tb = t0 + rr * 16 + hi * 4;
#pragma unroll
    for (int f = 0; f < 8; ++f) {
      const int d = f * 16 + fr;
      const ushort4 v4 = *(const ushort4*)(vt + ((size_t)g * 128 + d) * 2048 + tb);
      float u0 = m1v * b2f(v4.x) + m2v * (accO[rr][f][0] * rlq[rr][0]);
      float u1 = m1v * b2f(v4.y) + m2v * (accO[rr][f][1] * rlq[rr][1]);
      float u2 = m1v * b2f(v4.z) + m2v * (accO[rr][f][2] * rlq[rr][2]);
      float u3 = m1v * b2f(v4.w) + m2v * (accO[rr][f][3] * rlq[rr][3]);
      *(uint2*)(y1u + ((size_t)bh * 128 + d) * 2048 + tb) =
          make_uint2(pk2(u0, u1), pk2(u2, u3));
    }
  }
  if (hi == 0) {
#pragma unroll
    for (int rr = 0; rr < 2; ++rr)
      Lb[(size_t)bh * 2048 + t0 + rr * 16 + fr] = lsum[rr];
  }
}

// ---------------- attention pass 2: ymix = att @ u  (direct final output) ----------------
__global__ __launch_bounds__(256, 2) void attn_pass2_kernel(
    const __hip_bfloat16* __restrict__ qT,
    const __hip_bfloat16* __restrict__ kT,
    const __hip_bfloat16* __restrict__ y1u,  // (B,H,HD,T)
    const float* __restrict__ Lb,
    __hip_bfloat16* __restrict__ ymix) {     // (B,T,C)
  __shared__ __align__(16) __hip_bfloat16 Ks[2][64 * 128];
  __shared__ __align__(16) __hip_bfloat16 Vs[2][128 * 64];
  __shared__ __align__(16) char Ps[4][32 * 128];
  const int tid = threadIdx.x, lane = tid & 63, wid = tid >> 6;
  const int bi = blockIdx.x;
  const int u = bi & 255, half = bi >> 8;
  const int g = u & 7;
  const int pslot = (u >> 3) & 7;
  const int bh = g * 4 + (u >> 6);
  const int h = bh & 15, b = bh >> 4;
  const int j = half ? (15 - pslot) : pslot;
  const int q0 = j * 128;
  const int nt = 2 * j + 2;
  const int sd = 2 * j + (wid >> 1);
  const __hip_bfloat16* Kp = kT + (size_t)g * 2048 * 128;
  const __hip_bfloat16* Yp = y1u + (size_t)bh * 128 * 2048;
  const int fr = lane & 15, hi = lane >> 4;

  bf16x8 qf[2][4];
  float rl[2];
  {
    const __hip_bfloat16* Qp = qT + ((size_t)bh * 2048 + q0 + wid * 32) * 128;
#pragma unroll
    for (int rr = 0; rr < 2; ++rr)
#pragma unroll
      for (int dc = 0; dc < 4; ++dc)
        qf[rr][dc] = *(const bf16x8*)(Qp + (rr * 16 + fr) * 128 + dc * 32 + hi * 8);
    const size_t qb = (size_t)bh * 2048 + q0 + wid * 32;
    rl[0] = 1.f / Lb[qb + fr];
    rl[1] = 1.f / Lb[qb + 16 + fr];
  }

  f32x4 accO[2][8] = {};
  char* Pb = Ps[wid];

  auto STAGE = [&](int buf, int kt) {
    const int k0 = kt * 64;
#pragma unroll
    for (int i = 0; i < 4; ++i) {
      int f = i * 256 + tid;
      int r = f >> 4, s = f & 15, sx = s ^ (r & 7);
      gload_lds16(Kp + (size_t)(k0 + r) * 128 + sx * 8,
                  (char*)Ks[buf] + (i * 256 + wid * 64) * 16);
    }
#pragma unroll
    for (int i = 0; i < 4; ++i) {
      int f = i * 256 + tid;
      int r = f >> 3, s = f & 7, sx = s ^ (r & 7);
      gload_lds16(Yp + (size_t)r * 2048 + k0 + sx * 8,
                  (char*)Vs[buf] + (i * 256 + wid * 64) * 16);
    }
  };

  STAGE(0, 0);
  for (int s = 0; s < nt; ++s) {
    if (s > 0) __builtin_amdgcn_s_barrier();
    __builtin_amdgcn_sched_barrier(0);
    if (s + 1 < nt) STAGE((s + 1) & 1, s + 1);
    __builtin_amdgcn_sched_barrier(0);
    if (s + 1 < nt) asm volatile("s_waitcnt vmcnt(8)" ::: "memory");
    else            asm volatile("s_waitcnt vmcnt(0)" ::: "memory");
    __builtin_amdgcn_s_barrier();
    __builtin_amdgcn_sched_barrier(0);

    if (s <= sd) {
      const char* Kc = (const char*)Ks[s & 1];
      f32x4 sf[2][4] = {};
      __builtin_amdgcn_s_setprio(1);
#pragma unroll
      for (int c = 0; c < 4; ++c) {
        const int krow = c * 16 + fr;
#pragma unroll
        for (int dc = 0; dc < 4; ++dc) {
          int slot = (dc * 4 + hi) ^ (krow & 7);
          bf16x8 kf = *(const bf16x8*)(Kc + krow * 256 + slot * 16);
          sf[0][c] = MFMA_BF16(kf, qf[0][dc], sf[0][c]);
          sf[1][c] = MFMA_BF16(kf, qf[1][dc], sf[1][c]);
        }
      }
      __builtin_amdgcn_s_setprio(0);
      // normalize P with static max + stored denominator (no shuffles)
      if (s == sd) {
#pragma unroll
        for (int rr = 0; rr < 2; ++rr) {
          const int qq = q0 + wid * 32 + rr * 16 + fr;
#pragma unroll
          for (int c = 0; c < 4; ++c) {
            const int kb = s * 64 + c * 16 + hi * 4;
#pragma unroll
            for (int r = 0; r < 4; ++r)
              if (kb + r > qq) sf[rr][c][r] = -1e30f;
          }
        }
      }
#pragma unroll
      for (int rr = 0; rr < 2; ++rr)
#pragma unroll
        for (int c = 0; c < 4; ++c)
#pragma unroll
          for (int r = 0; r < 4; ++r)
            sf[rr][c][r] = __builtin_amdgcn_exp2f(sf[rr][c][r] - SMAX) * rl[rr];
#pragma unroll
      for (int rr = 0; rr < 2; ++rr) {
        const int row = rr * 16 + fr;
        char* Prow = Pb + row * 128;
#pragma unroll
        for (int c = 0; c < 4; ++c) {
          uint32_t w0 = pk2(sf[rr][c][0], sf[rr][c][1]);
          uint32_t w1 = pk2(sf[rr][c][2], sf[rr][c][3]);
          int sl = (c * 2 + (hi >> 1)) ^ (row & 7);
          *(uint2*)(Prow + sl * 16 + (hi & 1) * 8) = make_uint2(w0, w1);
        }
      }
      bf16x8 pf[2][2];
#pragma unroll
      for (int rr = 0; rr < 2; ++rr) {
        const int row = rr * 16 + fr;
#pragma unroll
        for (int kc = 0; kc < 2; ++kc) {
          int sl = (kc * 4 + hi) ^ (row & 7);
          pf[rr][kc] = *(const bf16x8*)(Pb + row * 128 + sl * 16);
        }
      }
      const __hip_bfloat16* Vc = Vs[s & 1];
      __builtin_amdgcn_s_setprio(1);
#pragma unroll
      for (int kc = 0; kc < 2; ++kc)
#pragma unroll
        for (int f = 0; f < 8; ++f) {
          int vrow = f * 16 + fr;
          int vslot = (kc * 4 + hi) ^ (fr & 7);
          bf16x8 vf = *(const bf16x8*)(Vc + vrow * 64 + vslot * 8);
          accO[0][f] = MFMA_BF16(pf[0][kc], vf, accO[0][f]);
          accO[1][f] = MFMA_BF16(pf[1][kc], vf, accO[1][f]);
        }
      __builtin_amdgcn_s_setprio(0);
    }
  }

  // accO already IS the final mixed output (P pre-normalized, u pre-mixed)
#pragma unroll
  for (int rr = 0; rr < 2; ++rr) {
#pragma unroll
    for (int f = 0; f < 8; ++f) {
      const int d = f * 16 + fr;
#pragma unroll
      for (int r = 0; r < 4; ++r) {
        int q = q0 + wid * 32 + rr * 16 + hi * 4 + r;
        ymix[((size_t)b * 2048 + q) * 2048 + h * 128 + d] = __float2bfloat16(accO[rr][f][r]);
      }
    }
  }
}

// ---------------- launch ----------------
extern "C" void kernel_launch(void* const* d_in, const int* in_sizes, int n_in,
                              void* d_out, int out_size, void* d_ws, size_t ws_size,
                              hipStream_t stream) {
  const float* x    = (const float*)d_in[0];
  const float* cosb = (const float*)d_in[1];
  const float* sinb = (const float*)d_in[2];
  const float* Wq   = (const float*)d_in[3];
  const float* Wk   = (const float*)d_in[4];
  const float* Wv   = (const float*)d_in[5];
  const float* Wp   = (const float*)d_in[6];
  const float* mix1 = (const float*)d_in[7];
  const float* mix2 = (const float*)d_in[8];
  float* out = (float*)d_out;
  char* ws = (char*)d_ws;

  // workspace layout (bytes), peak ~80 MB
  __hip_bfloat16* xb   = (__hip_bfloat16*)(ws + 0);            // 16.78 MB; reused as ymix
  __hip_bfloat16* WTa  = (__hip_bfloat16*)(ws + 16777216);     // 12.58 MB
  __hip_bfloat16* WpT  = (__hip_bfloat16*)(ws + 29360128);     // 8.39 MB
  __hip_bfloat16* y1u  = (__hip_bfloat16*)(ws + 37748736);     // 16.78 MB
  float*          Lb   = (float*)(ws + 54525952);              // 0.26 MB
  __hip_bfloat16* qTb  = (__hip_bfloat16*)(ws + 55050240);     // 16.78 MB
  __hip_bfloat16* kTb  = (__hip_bfloat16*)(ws + 71827456);     // 4.19 MB
  __hip_bfloat16* vtb  = (__hip_bfloat16*)(ws + 76021760);     // 4.19 MB
  __hip_bfloat16* ymix = (__hip_bfloat16*)(ws + 0);

  dim3 tb(32, 8);
  prep_kernel<<<18432, tb, 0, stream>>>(x, xb, Wq, Wk, Wv, Wp, WTa, WpT);

  // fused QKV projection + RoPE + RMS + V-transpose (128x128 tiles, BK=64, 768 blocks)
  gemm_qkv_rope_kernel<<<768, 256, 0, stream>>>(xb, WTa, cosb, sinb, qTb, kTb, vtb);

  attn_pass1_kernel<<<512, 256, 0, stream>>>(qTb, kTb, vtb, y1u, Lb, mix1, mix2);
  attn_pass2_kernel<<<512, 256, 0, stream>>>(qTb, kTb, y1u, Lb, ymix);

  gemm_bf16_kernel<<<512, 256, 0, stream>>>(ymix, WpT, out, 4096, 2048, 2048);
}

// Round 18
// 231.371 us; speedup vs baseline: 1.0344x; 1.0103x over previous
//
#include <hip/hip_runtime.h>
#include <hip/hip_bf16.h>
#include <cstdint>
#include <cstddef>

#define AS1 __attribute__((address_space(1)))
#define AS3 __attribute__((address_space(3)))

typedef __attribute__((ext_vector_type(8))) short bf16x8;
typedef __attribute__((ext_vector_type(4))) float f32x4;

__device__ __forceinline__ void gload_lds16(const void* g, void* l) {
  __builtin_amdgcn_global_load_lds((const AS1 void*)g, (AS3 void*)l, 16, 0, 0);
}

#define MFMA_BF16(A, B, C) __builtin_amdgcn_mfma_f32_16x16x32_bf16((A), (B), (C), 0, 0, 0)

// (1/sqrt(128)) * log2(e) — folded into q at rope time; softmax runs in exp2 domain.
#define QSCALE 0.12751744f
// STATIC softmax max: q,k RMS-normalized => |q.k|_exp2 <= sqrt(128)*log2(e) = 16.32.
// exp2(s - SMAX) <= 1 always, so online max tracking is unnecessary (exact softmax).
#define SMAX 16.5f

__device__ __forceinline__ uint32_t pk2(float a, float b) {
  uint32_t ua = (uint32_t)__builtin_bit_cast(unsigned short, __float2bfloat16(a));
  uint32_t ub = (uint32_t)__builtin_bit_cast(unsigned short, __float2bfloat16(b));
  return ua | (ub << 16);
}
__device__ __forceinline__ float b2f(unsigned short u) {
  return __builtin_bit_cast(float, (uint32_t)u << 16);
}

// sum over 8 consecutive lanes (group-aligned): DPP xor1, xor2, half-mirror
__device__ __forceinline__ float red8_sum(float v) {
  int x;
  x = __builtin_amdgcn_update_dpp(0, __builtin_bit_cast(int, v), 0xB1, 0xF, 0xF, true);
  v += __builtin_bit_cast(float, x);
  x = __builtin_amdgcn_update_dpp(0, __builtin_bit_cast(int, v), 0x4E, 0xF, 0xF, true);
  v += __builtin_bit_cast(float, x);
  x = __builtin_amdgcn_update_dpp(0, __builtin_bit_cast(int, v), 0x141, 0xF, 0xF, true);
  v += __builtin_bit_cast(float, x);
  return v;
}

// ---------------- merged prep: x cast + weight transposes in one launch ----------------
__global__ __launch_bounds__(256) void prep_kernel(const float* __restrict__ x,
                                                   __hip_bfloat16* __restrict__ xb,
                                                   const float* __restrict__ Wq,
                                                   const float* __restrict__ Wk,
                                                   const float* __restrict__ Wv,
                                                   const float* __restrict__ Wp,
                                                   __hip_bfloat16* __restrict__ WTa,
                                                   __hip_bfloat16* __restrict__ WpT) {
  __shared__ float tile[32][33];
  int id = blockIdx.x;
  int tx = threadIdx.x, ty = threadIdx.y;
  if (id < 8192) {
    int i = id * 256 + ty * 32 + tx;
    float4 v = ((const float4*)x)[i];
    __hip_bfloat16* o = xb + (size_t)i * 4;
    o[0] = __float2bfloat16(v.x);
    o[1] = __float2bfloat16(v.y);
    o[2] = __float2bfloat16(v.z);
    o[3] = __float2bfloat16(v.w);
    return;
  }
  id -= 8192;
  const float* in; __hip_bfloat16* out; int is, os, bx, by;
  if (id < 4096)      { in = Wq; out = WTa;                          is = 2048; os = 2048; bx = id & 63; by = id >> 6; }
  else if (id < 5120) { int t = id - 4096; in = Wk; out = WTa + (size_t)2048 * 2048; is = 512; os = 2048; bx = t & 15; by = t >> 4; }
  else if (id < 6144) { int t = id - 5120; in = Wv; out = WTa + (size_t)2560 * 2048; is = 512; os = 2048; bx = t & 15; by = t >> 4; }
  else                { int t = id - 6144; in = Wp; out = WpT;       is = 2048; os = 2048; bx = t & 63; by = t >> 6; }
  int c0 = bx * 32, r0 = by * 32;
#pragma unroll
  for (int i = 0; i < 32; i += 8)
    tile[ty + i][tx] = in[(size_t)(r0 + ty + i) * is + c0 + tx];
  __syncthreads();
#pragma unroll
  for (int i = 0; i < 32; i += 8)
    out[(size_t)(c0 + ty + i) * os + r0 + tx] = __float2bfloat16(tile[tx][ty + i]);
}

// ---------------- qkv GEMM: 128x128 tile, BK=64, 4 waves, 2-phase counted-vmcnt ----------------
__global__ __launch_bounds__(256, 2) void gemm_qkv_rope_kernel(
    const __hip_bfloat16* __restrict__ A,
    const __hip_bfloat16* __restrict__ Bt,
    const float* __restrict__ cosb,
    const float* __restrict__ sinb,
    __hip_bfloat16* __restrict__ qT,
    __hip_bfloat16* __restrict__ kT,
    __hip_bfloat16* __restrict__ vt) {
  __shared__ __align__(16) char smem[65536];
  __hip_bfloat16* CL4 = (__hip_bfloat16*)smem;    // elem idx = (q4*133+col)*4 + rr
  const int K = 2048;
  const int tid = threadIdx.x;
  const int lane = tid & 63;
  const int wid = tid >> 6;
  const int wm = wid >> 1, wn = wid & 1;
  const int bid = blockIdx.x;
  const int swz = (bid & 7) * 96 + (bid >> 3);
  const int tm = swz / 24, tn = swz % 24;
  const int row0 = tm << 7, col0 = tn << 7;
  const int fr = lane & 15, hi = lane >> 4;

  auto STAGE = [&](int buf, int k0) {
#pragma unroll
    for (int i = 0; i < 4; ++i) {
      int f = i * 256 + tid;
      int r = f >> 3, s = f & 7, sx = s ^ (r & 7);
      gload_lds16(A + (size_t)(row0 + r) * K + k0 + sx * 8,
                  smem + buf * 16384 + f * 16);
    }
#pragma unroll
    for (int i = 0; i < 4; ++i) {
      int f = i * 256 + tid;
      int r = f >> 3, s = f & 7, sx = s ^ (r & 7);
      gload_lds16(Bt + (size_t)(col0 + r) * K + k0 + sx * 8,
                  smem + 32768 + buf * 16384 + f * 16);
    }
  };

  f32x4 acc[4][4] = {};
  STAGE(0, 0);
  int cur = 0;
  for (int kk = 0; kk < 32; ++kk) {
    if (kk > 0) __builtin_amdgcn_s_barrier();
    __builtin_amdgcn_sched_barrier(0);
    if (kk + 1 < 32) STAGE(cur ^ 1, (kk + 1) * 64);
    __builtin_amdgcn_sched_barrier(0);
    if (kk + 1 < 32) asm volatile("s_waitcnt vmcnt(8)" ::: "memory");
    else             asm volatile("s_waitcnt vmcnt(0)" ::: "memory");
    __builtin_amdgcn_s_barrier();
    __builtin_amdgcn_sched_barrier(0);
    const char* Ac = smem + cur * 16384;
    const char* Bc = smem + 32768 + cur * 16384;
#pragma unroll
    for (int kh = 0; kh < 2; ++kh) {
      bf16x8 af[4], bfr[4];
#pragma unroll
      for (int n = 0; n < 4; ++n) {
        int rowb = wn * 64 + n * 16 + fr;
        int sl = (kh * 4 + hi) ^ (rowb & 7);
        bfr[n] = *(const bf16x8*)(Bc + rowb * 128 + sl * 16);
      }
#pragma unroll
      for (int m = 0; m < 4; ++m) {
        int rowa = wm * 64 + m * 16 + fr;
        int sl = (kh * 4 + hi) ^ (rowa & 7);
        af[m] = *(const bf16x8*)(Ac + rowa * 128 + sl * 16);
      }
      __builtin_amdgcn_s_setprio(1);
#pragma unroll
      for (int m = 0; m < 4; ++m)
#pragma unroll
        for (int n = 0; n < 4; ++n)
          acc[m][n] = MFMA_BF16(af[m], bfr[n], acc[m][n]);
      __builtin_amdgcn_s_setprio(0);
    }
    cur ^= 1;
  }
  __syncthreads();

  // ---- pack acc -> CL4 ----
#pragma unroll
  for (int m = 0; m < 4; ++m)
#pragma unroll
    for (int n = 0; n < 4; ++n) {
      int q4 = wm * 16 + m * 4 + hi;
      int col = wn * 64 + n * 16 + fr;
      *(uint2*)(CL4 + ((q4 * 133 + col) << 2)) =
          make_uint2(pk2(acc[m][n][0], acc[m][n][1]), pk2(acc[m][n][2], acc[m][n][3]));
    }
  __syncthreads();

  const int b = row0 >> 11;
  const int t0 = row0 & 2047;

  if (col0 >= 2560) {
    const int hv = (col0 - 2560) >> 7;
    __hip_bfloat16* vb = vt + (size_t)(b * 4 + hv) * 128 * 2048;
    const int col = tid >> 1, th = tid & 1;
    uint2 w[16];
#pragma unroll
    for (int qq = 0; qq < 16; ++qq)
      w[qq] = *(const uint2*)(CL4 + (((th * 16 + qq) * 133 + col) << 2));
    __hip_bfloat16* dstv = vb + (size_t)col * 2048 + t0 + th * 64;
#pragma unroll
    for (int e = 0; e < 8; ++e)
      *(uint4*)(dstv + e * 8) = make_uint4(w[2 * e].x, w[2 * e].y, w[2 * e + 1].x, w[2 * e + 1].y);
    return;
  }

  const int quad = tid >> 3, cp = tid & 7;
  const int tb = t0 + quad * 4;
  bf16x8 lov[4], hiv[4];
#pragma unroll
  for (int e = 0; e < 4; ++e) {
    lov[e] = *(const bf16x8*)(CL4 + ((quad * 133 + cp * 8 + e * 2) << 2));
    hiv[e] = *(const bf16x8*)(CL4 + ((quad * 133 + 64 + cp * 8 + e * 2) << 2));
  }
  const float oscale = (col0 < 2048) ? QSCALE : 1.0f;
  __hip_bfloat16* dstq = (col0 < 2048)
      ? qT + (size_t)(b * 16 + (col0 >> 7)) * 2048 * 128
      : kT + (size_t)(b * 4 + ((col0 - 2048) >> 7)) * 2048 * 128;

  float o1v[4][8], o2v[4][8], ssum[4];
#pragma unroll
  for (int rr = 0; rr < 4; ++rr) {
    const float* cb = cosb + (size_t)(tb + rr) * 64 + cp * 8;
    const float* sb = sinb + (size_t)(tb + rr) * 64 + cp * 8;
    float4 c0 = *(const float4*)cb, c1 = *(const float4*)(cb + 4);
    float4 s0 = *(const float4*)sb, s1 = *(const float4*)(sb + 4);
    float cc[8] = {c0.x, c0.y, c0.z, c0.w, c1.x, c1.y, c1.z, c1.w};
    float sn[8] = {s0.x, s0.y, s0.z, s0.w, s1.x, s1.y, s1.z, s1.w};
    float ss = 0.f;
#pragma unroll
    for (int e = 0; e < 4; ++e)
#pragma unroll
      for (int w2 = 0; w2 < 2; ++w2) {
        int pd = e * 2 + w2;
        float x1 = b2f((unsigned short)lov[e][w2 * 4 + rr]);
        float x2 = b2f((unsigned short)hiv[e][w2 * 4 + rr]);
        float a = x1 * cc[pd] - x2 * sn[pd];
        float bb = x1 * sn[pd] + x2 * cc[pd];
        o1v[rr][pd] = a;
        o2v[rr][pd] = bb;
        ss += a * a + bb * bb;
      }
    ssum[rr] = ss;
  }
#pragma unroll
  for (int rr = 0; rr < 4; ++rr) {
    float rn = rsqrtf(red8_sum(ssum[rr]) * (1.f / 128.f) + 1e-6f) * oscale;
    __hip_bfloat16* dr = dstq + (size_t)(tb + rr) * 128 + cp * 8;
    *(uint4*)dr = make_uint4(pk2(o1v[rr][0] * rn, o1v[rr][1] * rn),
                             pk2(o1v[rr][2] * rn, o1v[rr][3] * rn),
                             pk2(o1v[rr][4] * rn, o1v[rr][5] * rn),
                             pk2(o1v[rr][6] * rn, o1v[rr][7] * rn));
    *(uint4*)(dr + 64) = make_uint4(pk2(o2v[rr][0] * rn, o2v[rr][1] * rn),
                                    pk2(o2v[rr][2] * rn, o2v[rr][3] * rn),
                                    pk2(o2v[rr][4] * rn, o2v[rr][5] * rn),
                                    pk2(o2v[rr][6] * rn, o2v[rr][7] * rn));
  }
}

// ---------------- generic bf16 GEMM: 128x128 tile, BK=64, swizzled (f32 out) ----------------
__global__ __launch_bounds__(256, 2) void gemm_bf16_kernel(const __hip_bfloat16* __restrict__ A,
                                                           const __hip_bfloat16* __restrict__ Bt,
                                                           float* __restrict__ C,
                                                           int M, int N, int K) {
  __shared__ __align__(16) char smem[65536];
  const int tid = threadIdx.x;
  const int lane = tid & 63;
  const int wid = tid >> 6;
  const int wm = wid >> 1, wn = wid & 1;
  const int nwg = gridDim.x;
  const int bid = blockIdx.x;
  const int swz = (bid & 7) * (nwg >> 3) + (bid >> 3);
  const int ntile = N >> 7;
  const int tm = swz / ntile, tn = swz % ntile;
  const int row0 = tm << 7, col0 = tn << 7;
  const int fr = lane & 15, hi = lane >> 4;

  auto STAGE = [&](int buf, int k0) {
#pragma unroll
    for (int i = 0; i < 4; ++i) {
      int f = i * 256 + tid;
      int r = f >> 3, s = f & 7, sx = s ^ (r & 7);
      gload_lds16(A + (size_t)(row0 + r) * K + k0 + sx * 8,
                  smem + buf * 16384 + f * 16);
    }
#pragma unroll
    for (int i = 0; i < 4; ++i) {
      int f = i * 256 + tid;
      int r = f >> 3, s = f & 7, sx = s ^ (r & 7);
      gload_lds16(Bt + (size_t)(col0 + r) * K + k0 + sx * 8,
                  smem + 32768 + buf * 16384 + f * 16);
    }
  };

  f32x4 acc[4][4] = {};
  const int nk = K >> 6;
  STAGE(0, 0);
  int cur = 0;
  for (int kk = 0; kk < nk; ++kk) {
    if (kk > 0) __builtin_amdgcn_s_barrier();
    __builtin_amdgcn_sched_barrier(0);
    if (kk + 1 < nk) STAGE(cur ^ 1, (kk + 1) * 64);
    __builtin_amdgcn_sched_barrier(0);
    if (kk + 1 < nk) asm volatile("s_waitcnt vmcnt(8)" ::: "memory");
    else             asm volatile("s_waitcnt vmcnt(0)" ::: "memory");
    __builtin_amdgcn_s_barrier();
    __builtin_amdgcn_sched_barrier(0);
    const char* Ac = smem + cur * 16384;
    const char* Bc = smem + 32768 + cur * 16384;
#pragma unroll
    for (int kh = 0; kh < 2; ++kh) {
      bf16x8 af[4], bfr[4];
#pragma unroll
      for (int n = 0; n < 4; ++n) {
        int rowb = wn * 64 + n * 16 + fr;
        int sl = (kh * 4 + hi) ^ (rowb & 7);
        bfr[n] = *(const bf16x8*)(Bc + rowb * 128 + sl * 16);
      }
#pragma unroll
      for (int m = 0; m < 4; ++m) {
        int rowa = wm * 64 + m * 16 + fr;
        int sl = (kh * 4 + hi) ^ (rowa & 7);
        af[m] = *(const bf16x8*)(Ac + rowa * 128 + sl * 16);
      }
      __builtin_amdgcn_s_setprio(1);
#pragma unroll
      for (int m = 0; m < 4; ++m)
#pragma unroll
        for (int n = 0; n < 4; ++n)
          acc[m][n] = MFMA_BF16(af[m], bfr[n], acc[m][n]);
      __builtin_amdgcn_s_setprio(0);
    }
    cur ^= 1;
  }

  const int cr = hi * 4;
#pragma unroll
  for (int m = 0; m < 4; ++m)
#pragma unroll
    for (int n = 0; n < 4; ++n) {
      int col = col0 + wn * 64 + n * 16 + fr;
#pragma unroll
      for (int r = 0; r < 4; ++r) {
        int row = row0 + wm * 64 + m * 16 + cr + r;
        C[(size_t)row * N + col] = acc[m][n][r];
      }
    }
}

// block decode (both passes): bi in [0,512): u=bi&255, half=bi>>8. g=u&7 = (b*4+kvh).
// bi and bi+256 (two halves of a balanced 34-step pair) land on the same CU under rr
// dispatch: per-CU balance at 2 blocks/CU.
//
// STATIC-MAX SOFTMAX: no online max tracking (scores bounded by SMAX); P = exp2(s-SMAX),
// l accumulated per-lane, reduced once in the epilogue. Zero cross-lane ops in the loop.

// ---------------- attention pass 1: y1 = softmax(qk^T) v ; writes u = mix1*v + mix2*y1 ----------------
__global__ __launch_bounds__(256, 2) void attn_pass1_kernel(
    const __hip_bfloat16* __restrict__ qT,   // (B,H,T,HD), q pre-scaled
    const __hip_bfloat16* __restrict__ kT,   // (B,HK,T,HD)
    const __hip_bfloat16* __restrict__ vt,   // (B,HK,HD,T)
    __hip_bfloat16* __restrict__ y1u,        // (B,H,HD,T)  u = mix1*v + mix2*y1
    float* __restrict__ Lb,                  // (B,H,T)
    const float* __restrict__ mix1p,
    const float* __restrict__ mix2p) {
  __shared__ __align__(16) __hip_bfloat16 Ks[2][64 * 128];
  __shared__ __align__(16) __hip_bfloat16 Vs[2][128 * 64];
  __shared__ __align__(16) char Ps[4][32 * 128];
  const int tid = threadIdx.x, lane = tid & 63, wid = tid >> 6;   // wid 0..3
  const int bi = blockIdx.x;
  const int u = bi & 255, half = bi >> 8;
  const int g = u & 7;
  const int pslot = (u >> 3) & 7;
  const int bh = g * 4 + (u >> 6);
  const int j = half ? (15 - pslot) : pslot;
  const int q0 = j * 128;
  const int nt = 2 * j + 2;                  // even
  const int sd = 2 * j + (wid >> 1);
  const __hip_bfloat16* Kp = kT + (size_t)g * 2048 * 128;
  const __hip_bfloat16* Vp = vt + (size_t)g * 128 * 2048;
  const int fr = lane & 15, hi = lane >> 4;

  bf16x8 qf[2][4];
  {
    const __hip_bfloat16* Qp = qT + ((size_t)bh * 2048 + q0 + wid * 32) * 128;
#pragma unroll
    for (int rr = 0; rr < 2; ++rr)
#pragma unroll
      for (int dc = 0; dc < 4; ++dc)
        qf[rr][dc] = *(const bf16x8*)(Qp + (rr * 16 + fr) * 128 + dc * 32 + hi * 8);
  }

  f32x4 accO[2][8] = {};
  float l[2] = {0.f, 0.f};                   // per-lane partial denominators

  char* Pb = Ps[wid];

  auto STAGE = [&](int buf, int kt) {        // 8 global_load_lds (4 K + 4 V)
    const int k0 = kt * 64;
#pragma unroll
    for (int i = 0; i < 4; ++i) {
      int f = i * 256 + tid;
      int r = f >> 4, s = f & 15, sx = s ^ (r & 7);
      gload_lds16(Kp + (size_t)(k0 + r) * 128 + sx * 8,
                  (char*)Ks[buf] + (i * 256 + wid * 64) * 16);
    }
#pragma unroll
    for (int i = 0; i < 4; ++i) {
      int f = i * 256 + tid;
      int r = f >> 3, s = f & 7, sx = s ^ (r & 7);
      gload_lds16(Vp + (size_t)r * 2048 + k0 + sx * 8,
                  (char*)Vs[buf] + (i * 256 + wid * 64) * 16);
    }
  };

  STAGE(0, 0);
  for (int s = 0; s < nt; ++s) {
    if (s > 0) __builtin_amdgcn_s_barrier();   // WAR: compute(s-1) closed
    __builtin_amdgcn_sched_barrier(0);
    if (s + 1 < nt) STAGE((s + 1) & 1, s + 1);
    __builtin_amdgcn_sched_barrier(0);
    if (s + 1 < nt) asm volatile("s_waitcnt vmcnt(8)" ::: "memory");
    else            asm volatile("s_waitcnt vmcnt(0)" ::: "memory");
    __builtin_amdgcn_s_barrier();              // K(s),V(s) landed for all waves
    __builtin_amdgcn_sched_barrier(0);

    if (s <= sd) {
      // ---- QK (swapped): sf[rr][c][r] = S[q=rr*16+fr][k=c*16+hi*4+r] ----
      const char* Kc = (const char*)Ks[s & 1];
      f32x4 sf[2][4] = {};
      __builtin_amdgcn_s_setprio(1);
#pragma unroll
      for (int c = 0; c < 4; ++c) {
        const int krow = c * 16 + fr;
#pragma unroll
        for (int dc = 0; dc < 4; ++dc) {
          int slot = (dc * 4 + hi) ^ (krow & 7);
          bf16x8 kf = *(const bf16x8*)(Kc + krow * 256 + slot * 16);
          sf[0][c] = MFMA_BF16(kf, qf[0][dc], sf[0][c]);
          sf[1][c] = MFMA_BF16(kf, qf[1][dc], sf[1][c]);
        }
      }
      __builtin_amdgcn_s_setprio(0);
      // ---- mask (diagonal only) + static-max exp2 + per-lane partial sum ----
      if (s == sd) {
#pragma unroll
        for (int rr = 0; rr < 2; ++rr) {
          const int qq = q0 + wid * 32 + rr * 16 + fr;
#pragma unroll
          for (int c = 0; c < 4; ++c) {
            const int kb = s * 64 + c * 16 + hi * 4;
#pragma unroll
            for (int r = 0; r < 4; ++r)
              if (kb + r > qq) sf[rr][c][r] = -1e30f;
          }
        }
      }
#pragma unroll
      for (int rr = 0; rr < 2; ++rr) {
        float rs = 0.f;
#pragma unroll
        for (int c = 0; c < 4; ++c)
#pragma unroll
          for (int r = 0; r < 4; ++r) {
            float p = __builtin_amdgcn_exp2f(sf[rr][c][r] - SMAX);
            sf[rr][c][r] = p;
            rs += p;
          }
        l[rr] += rs;
      }
      // ---- P -> LDS (packed b64, swizzled) + A-frag readback ----
#pragma unroll
      for (int rr = 0; rr < 2; ++rr) {
        const int row = rr * 16 + fr;
        char* Prow = Pb + row * 128;
#pragma unroll
        for (int c = 0; c < 4; ++c) {
          uint32_t w0 = pk2(sf[rr][c][0], sf[rr][c][1]);
          uint32_t w1 = pk2(sf[rr][c][2], sf[rr][c][3]);
          int sl = (c * 2 + (hi >> 1)) ^ (row & 7);
          *(uint2*)(Prow + sl * 16 + (hi & 1) * 8) = make_uint2(w0, w1);
        }
      }
      bf16x8 pf[2][2];
#pragma unroll
      for (int rr = 0; rr < 2; ++rr) {
        const int row = rr * 16 + fr;
#pragma unroll
        for (int kc = 0; kc < 2; ++kc) {
          int sl = (kc * 4 + hi) ^ (row & 7);
          pf[rr][kc] = *(const bf16x8*)(Pb + row * 128 + sl * 16);
        }
      }
      // ---- PV ----
      const __hip_bfloat16* Vc = Vs[s & 1];
      __builtin_amdgcn_s_setprio(1);
#pragma unroll
      for (int kc = 0; kc < 2; ++kc)
#pragma unroll
        for (int f = 0; f < 8; ++f) {
          int vrow = f * 16 + fr;
          int vslot = (kc * 4 + hi) ^ (fr & 7);
          bf16x8 vf = *(const bf16x8*)(Vc + vrow * 64 + vslot * 8);
          accO[0][f] = MFMA_BF16(pf[0][kc], vf, accO[0][f]);
          accO[1][f] = MFMA_BF16(pf[1][kc], vf, accO[1][f]);
        }
      __builtin_amdgcn_s_setprio(0);
    }
  }

  // ---- epilogue: reduce per-lane l once; u = mix1*v + mix2*(accO/l); store l ----
  float lsum[2];
#pragma unroll
  for (int rr = 0; rr < 2; ++rr) {
    float v = l[rr];
    v += __shfl_xor(v, 16);
    v += __shfl_xor(v, 32);
    lsum[rr] = v;
  }
  const float m1v = mix1p[0], m2v = mix2p[0];
  float rlq[2][4];
#pragma unroll
  for (int rr = 0; rr < 2; ++rr) {
    float inv = 1.f / lsum[rr];
#pragma unroll
    for (int r = 0; r < 4; ++r) rlq[rr][r] = __shfl(inv, hi * 4 + r);
  }
  const int t0 = q0 + wid * 32;
#pragma unroll
  for (int rr = 0; rr < 2; ++rr) {
    const int tb = t0 + rr * 16 + hi * 4;
#pragma unroll
    for (int f = 0; f < 8; ++f) {
      const int d = f * 16 + fr;
      const ushort4 v4 = *(const ushort4*)(vt + ((size_t)g * 128 + d) * 2048 + tb);
      float u0 = m1v * b2f(v4.x) + m2v * (accO[rr][f][0] * rlq[rr][0]);
      float u1 = m1v * b2f(v4.y) + m2v * (accO[rr][f][1] * rlq[rr][1]);
      float u2 = m1v * b2f(v4.z) + m2v * (accO[rr][f][2] * rlq[rr][2]);
      float u3 = m1v * b2f(v4.w) + m2v * (accO[rr][f][3] * rlq[rr][3]);
      *(uint2*)(y1u + ((size_t)bh * 128 + d) * 2048 + tb) =
          make_uint2(pk2(u0, u1), pk2(u2, u3));
    }
  }
  if (hi == 0) {
#pragma unroll
    for (int rr = 0; rr < 2; ++rr)
      Lb[(size_t)bh * 2048 + t0 + rr * 16 + fr] = lsum[rr];
  }
}

// ---------------- attention pass 2: ymix = att @ u  (direct final output) ----------------
// QK-AHEAD pipeline (r14-verified skeleton): iter s computes QK(s+1) into sfN while
// pack+PV(s) run on sfC. K staged two-ahead, V one-ahead, counted vmcnt(8/4/0).
// Normalization DEFERRED to the epilogue (raw exp2 accumulated; one rlq multiply/row).
__global__ __launch_bounds__(256, 2) void attn_pass2_kernel(
    const __hip_bfloat16* __restrict__ qT,
    const __hip_bfloat16* __restrict__ kT,
    const __hip_bfloat16* __restrict__ y1u,  // (B,H,HD,T)
    const float* __restrict__ Lb,
    __hip_bfloat16* __restrict__ ymix) {     // (B,T,C)
  __shared__ __align__(16) __hip_bfloat16 Ks[2][64 * 128];
  __shared__ __align__(16) __hip_bfloat16 Vs[2][128 * 64];
  __shared__ __align__(16) char Ps[4][32 * 128];
  const int tid = threadIdx.x, lane = tid & 63, wid = tid >> 6;
  const int bi = blockIdx.x;
  const int u = bi & 255, half = bi >> 8;
  const int g = u & 7;
  const int pslot = (u >> 3) & 7;
  const int bh = g * 4 + (u >> 6);
  const int h = bh & 15, b = bh >> 4;
  const int j = half ? (15 - pslot) : pslot;
  const int q0 = j * 128;
  const int nt = 2 * j + 2;                  // even
  const int sd = 2 * j + (wid >> 1);
  const __hip_bfloat16* Kp = kT + (size_t)g * 2048 * 128;
  const __hip_bfloat16* Yp = y1u + (size_t)bh * 128 * 2048;
  const int fr = lane & 15, hi = lane >> 4;

  bf16x8 qf[2][4];
  float rl[2];
  {
    const __hip_bfloat16* Qp = qT + ((size_t)bh * 2048 + q0 + wid * 32) * 128;
#pragma unroll
    for (int rr = 0; rr < 2; ++rr)
#pragma unroll
      for (int dc = 0; dc < 4; ++dc)
        qf[rr][dc] = *(const bf16x8*)(Qp + (rr * 16 + fr) * 128 + dc * 32 + hi * 8);
    const size_t qb = (size_t)bh * 2048 + q0 + wid * 32;
    rl[0] = 1.f / Lb[qb + fr];
    rl[1] = 1.f / Lb[qb + 16 + fr];
  }

  f32x4 accO[2][8] = {};
  char* Pb = Ps[wid];

  auto STAGE_K = [&](int buf, int kt) {      // 4 loads/thread
    const int k0 = kt * 64;
#pragma unroll
    for (int i = 0; i < 4; ++i) {
      int f = i * 256 + tid;
      int r = f >> 4, s = f & 15, sx = s ^ (r & 7);
      gload_lds16(Kp + (size_t)(k0 + r) * 128 + sx * 8,
                  (char*)Ks[buf] + (i * 256 + wid * 64) * 16);
    }
  };
  auto STAGE_V = [&](int buf, int kt) {      // 4 loads/thread
    const int k0 = kt * 64;
#pragma unroll
    for (int i = 0; i < 4; ++i) {
      int f = i * 256 + tid;
      int r = f >> 3, s = f & 7, sx = s ^ (r & 7);
      gload_lds16(Yp + (size_t)r * 2048 + k0 + sx * 8,
                  (char*)Vs[buf] + (i * 256 + wid * 64) * 16);
    }
  };

  auto QK = [&](int t, f32x4 (&sf)[2][4]) {  // S(t) from Ks[t&1]
    const char* Kc = (const char*)Ks[t & 1];
#pragma unroll
    for (int rr = 0; rr < 2; ++rr)
#pragma unroll
      for (int c = 0; c < 4; ++c) sf[rr][c] = (f32x4){0.f, 0.f, 0.f, 0.f};
    __builtin_amdgcn_s_setprio(1);
#pragma unroll
    for (int c = 0; c < 4; ++c) {
      const int krow = c * 16 + fr;
#pragma unroll
      for (int dc = 0; dc < 4; ++dc) {
        int slot = (dc * 4 + hi) ^ (krow & 7);
        bf16x8 kf = *(const bf16x8*)(Kc + krow * 256 + slot * 16);
        sf[0][c] = MFMA_BF16(kf, qf[0][dc], sf[0][c]);
        sf[1][c] = MFMA_BF16(kf, qf[1][dc], sf[1][c]);
      }
    }
    __builtin_amdgcn_s_setprio(0);
  };

  auto STEP = [&](int s, f32x4 (&sfC)[2][4], f32x4 (&sfN)[2][4]) {
    __builtin_amdgcn_s_barrier();            // close compute(s-1)/prologue-QK
    __builtin_amdgcn_sched_barrier(0);
    if (s + 2 < nt) STAGE_K(s & 1, s + 2);
    if (s + 1 < nt) STAGE_V((s + 1) & 1, s + 1);
    __builtin_amdgcn_sched_barrier(0);
    if (s + 2 < nt)      asm volatile("s_waitcnt vmcnt(8)" ::: "memory");
    else if (s + 1 < nt) asm volatile("s_waitcnt vmcnt(4)" ::: "memory");
    else                 asm volatile("s_waitcnt vmcnt(0)" ::: "memory");
    __builtin_amdgcn_s_barrier();            // K(s+1), V(s) landed for all waves
    __builtin_amdgcn_sched_barrier(0);

    if (s + 1 <= sd) QK(s + 1, sfN);         // pipeline: next tile's scores

    if (s <= sd) {
      // ---- mask (diagonal only) + static-max exp2 (UNNORMALIZED) ----
      if (s == sd) {
#pragma unroll
        for (int rr = 0; rr < 2; ++rr) {
          const int qq = q0 + wid * 32 + rr * 16 + fr;
#pragma unroll
          for (int c = 0; c < 4; ++c) {
            const int kb = s * 64 + c * 16 + hi * 4;
#pragma unroll
            for (int r = 0; r < 4; ++r)
              if (kb + r > qq) sfC[rr][c][r] = -1e30f;
          }
        }
      }
#pragma unroll
      for (int rr = 0; rr < 2; ++rr)
#pragma unroll
        for (int c = 0; c < 4; ++c)
#pragma unroll
          for (int r = 0; r < 4; ++r)
            sfC[rr][c][r] = __builtin_amdgcn_exp2f(sfC[rr][c][r] - SMAX);
      // ---- P -> LDS (packed b64, swizzled) + A-frag readback ----
#pragma unroll
      for (int rr = 0; rr < 2; ++rr) {
        const int row = rr * 16 + fr;
        char* Prow = Pb + row * 128;
#pragma unroll
        for (int c = 0; c < 4; ++c) {
          uint32_t w0 = pk2(sfC[rr][c][0], sfC[rr][c][1]);
          uint32_t w1 = pk2(sfC[rr][c][2], sfC[rr][c][3]);
          int sl = (c * 2 + (hi >> 1)) ^ (row & 7);
          *(uint2*)(Prow + sl * 16 + (hi & 1) * 8) = make_uint2(w0, w1);
        }
      }
      bf16x8 pf[2][2];
#pragma unroll
      for (int rr = 0; rr < 2; ++rr) {
        const int row = rr * 16 + fr;
#pragma unroll
        for (int kc = 0; kc < 2; ++kc) {
          int sl = (kc * 4 + hi) ^ (row & 7);
          pf[rr][kc] = *(const bf16x8*)(Pb + row * 128 + sl * 16);
        }
      }
      // ---- PV from Vs[s&1] ----
      const __hip_bfloat16* Vc = Vs[s & 1];
      __builtin_amdgcn_s_setprio(1);
#pragma unroll
      for (int kc = 0; kc < 2; ++kc)
#pragma unroll
        for (int f = 0; f < 8; ++f) {
          int vrow = f * 16 + fr;
          int vslot = (kc * 4 + hi) ^ (fr & 7);
          bf16x8 vf = *(const bf16x8*)(Vc + vrow * 64 + vslot * 8);
          accO[0][f] = MFMA_BF16(pf[0][kc], vf, accO[0][f]);
          accO[1][f] = MFMA_BF16(pf[1][kc], vf, accO[1][f]);
        }
      __builtin_amdgcn_s_setprio(0);
    }
  };

  // prologue: K0, V0, K1 staged; QK(0)
  f32x4 sfA[2][4], sfB[2][4];
  STAGE_K(0, 0);
  STAGE_V(0, 0);
  STAGE_K(1, 1);
  asm volatile("s_waitcnt vmcnt(8)" ::: "memory");   // K0 landed (V0, K1 in flight)
  __builtin_amdgcn_s_barrier();
  __builtin_amdgcn_sched_barrier(0);
  QK(0, sfA);

  for (int s2 = 0; s2 < nt; s2 += 2) {
    STEP(s2, sfA, sfB);
    STEP(s2 + 1, sfB, sfA);
  }

  // ---- epilogue: normalize per q-row once (rlq via shuffle), write final output ----
  float rlq[2][4];
#pragma unroll
  for (int rr = 0; rr < 2; ++rr)
#pragma unroll
    for (int r = 0; r < 4; ++r) rlq[rr][r] = __shfl(rl[rr], hi * 4 + r);
#pragma unroll
  for (int rr = 0; rr < 2; ++rr) {
#pragma unroll
    for (int f = 0; f < 8; ++f) {
      const int d = f * 16 + fr;
#pragma unroll
      for (int r = 0; r < 4; ++r) {
        int q = q0 + wid * 32 + rr * 16 + hi * 4 + r;
        ymix[((size_t)b * 2048 + q) * 2048 + h * 128 + d] =
            __float2bfloat16(accO[rr][f][r] * rlq[rr][r]);
      }
    }
  }
}

// ---------------- launch ----------------
extern "C" void kernel_launch(void* const* d_in, const int* in_sizes, int n_in,
                              void* d_out, int out_size, void* d_ws, size_t ws_size,
                              hipStream_t stream) {
  const float* x    = (const float*)d_in[0];
  const float* cosb = (const float*)d_in[1];
  const float* sinb = (const float*)d_in[2];
  const float* Wq   = (const float*)d_in[3];
  const float* Wk   = (const float*)d_in[4];
  const float* Wv   = (const float*)d_in[5];
  const float* Wp   = (const float*)d_in[6];
  const float* mix1 = (const float*)d_in[7];
  const float* mix2 = (const float*)d_in[8];
  float* out = (float*)d_out;
  char* ws = (char*)d_ws;

  // workspace layout (bytes), peak ~80 MB
  __hip_bfloat16* xb   = (__hip_bfloat16*)(ws + 0);            // 16.78 MB; reused as ymix
  __hip_bfloat16* WTa  = (__hip_bfloat16*)(ws + 16777216);     // 12.58 MB
  __hip_bfloat16* WpT  = (__hip_bfloat16*)(ws + 29360128);     // 8.39 MB
  __hip_bfloat16* y1u  = (__hip_bfloat16*)(ws + 37748736);     // 16.78 MB
  float*          Lb   = (float*)(ws + 54525952);              // 0.26 MB
  __hip_bfloat16* qTb  = (__hip_bfloat16*)(ws + 55050240);     // 16.78 MB
  __hip_bfloat16* kTb  = (__hip_bfloat16*)(ws + 71827456);     // 4.19 MB
  __hip_bfloat16* vtb  = (__hip_bfloat16*)(ws + 76021760);     // 4.19 MB
  __hip_bfloat16* ymix = (__hip_bfloat16*)(ws + 0);

  dim3 tb(32, 8);
  prep_kernel<<<18432, tb, 0, stream>>>(x, xb, Wq, Wk, Wv, Wp, WTa, WpT);

  // fused QKV projection + RoPE + RMS + V-transpose (128x128 tiles, BK=64, 768 blocks)
  gemm_qkv_rope_kernel<<<768, 256, 0, stream>>>(xb, WTa, cosb, sinb, qTb, kTb, vtb);

  attn_pass1_kernel<<<512, 256, 0, stream>>>(qTb, kTb, vtb, y1u, Lb, mix1, mix2);
  attn_pass2_kernel<<<512, 256, 0, stream>>>(qTb, kTb, y1u, Lb, ymix);

  gemm_bf16_kernel<<<512, 256, 0, stream>>>(ymix, WpT, out, 4096, 2048, 2048);
}

// Round 19
// 230.057 us; speedup vs baseline: 1.0403x; 1.0057x over previous
//
#include <hip/hip_runtime.h>
#include <hip/hip_bf16.h>
#include <cstdint>
#include <cstddef>

#define AS1 __attribute__((address_space(1)))
#define AS3 __attribute__((address_space(3)))

typedef __attribute__((ext_vector_type(8))) short bf16x8;
typedef __attribute__((ext_vector_type(4))) float f32x4;

__device__ __forceinline__ void gload_lds16(const void* g, void* l) {
  __builtin_amdgcn_global_load_lds((const AS1 void*)g, (AS3 void*)l, 16, 0, 0);
}

#define MFMA_BF16(A, B, C) __builtin_amdgcn_mfma_f32_16x16x32_bf16((A), (B), (C), 0, 0, 0)

// (1/sqrt(128)) * log2(e) — folded into q at rope time; softmax runs in exp2 domain.
#define QSCALE 0.12751744f
// STATIC softmax max: q,k RMS-normalized => |q.k|_exp2 <= sqrt(128)*log2(e) = 16.32.
// exp2(s - SMAX) <= 1 always, so online max tracking is unnecessary (exact softmax).
#define SMAX 16.5f

__device__ __forceinline__ uint32_t pk2(float a, float b) {
  uint32_t ua = (uint32_t)__builtin_bit_cast(unsigned short, __float2bfloat16(a));
  uint32_t ub = (uint32_t)__builtin_bit_cast(unsigned short, __float2bfloat16(b));
  return ua | (ub << 16);
}
__device__ __forceinline__ float b2f(unsigned short u) {
  return __builtin_bit_cast(float, (uint32_t)u << 16);
}

// sum over 8 consecutive lanes (group-aligned): DPP xor1, xor2, half-mirror
__device__ __forceinline__ float red8_sum(float v) {
  int x;
  x = __builtin_amdgcn_update_dpp(0, __builtin_bit_cast(int, v), 0xB1, 0xF, 0xF, true);
  v += __builtin_bit_cast(float, x);
  x = __builtin_amdgcn_update_dpp(0, __builtin_bit_cast(int, v), 0x4E, 0xF, 0xF, true);
  v += __builtin_bit_cast(float, x);
  x = __builtin_amdgcn_update_dpp(0, __builtin_bit_cast(int, v), 0x141, 0xF, 0xF, true);
  v += __builtin_bit_cast(float, x);
  return v;
}

// ---------------- merged prep: x cast + weight transposes in one launch ----------------
__global__ __launch_bounds__(256) void prep_kernel(const float* __restrict__ x,
                                                   __hip_bfloat16* __restrict__ xb,
                                                   const float* __restrict__ Wq,
                                                   const float* __restrict__ Wk,
                                                   const float* __restrict__ Wv,
                                                   const float* __restrict__ Wp,
                                                   __hip_bfloat16* __restrict__ WTa,
                                                   __hip_bfloat16* __restrict__ WpT) {
  __shared__ float tile[32][33];
  int id = blockIdx.x;
  int tx = threadIdx.x, ty = threadIdx.y;
  if (id < 8192) {
    int i = id * 256 + ty * 32 + tx;
    float4 v = ((const float4*)x)[i];
    __hip_bfloat16* o = xb + (size_t)i * 4;
    o[0] = __float2bfloat16(v.x);
    o[1] = __float2bfloat16(v.y);
    o[2] = __float2bfloat16(v.z);
    o[3] = __float2bfloat16(v.w);
    return;
  }
  id -= 8192;
  const float* in; __hip_bfloat16* out; int is, os, bx, by;
  if (id < 4096)      { in = Wq; out = WTa;                          is = 2048; os = 2048; bx = id & 63; by = id >> 6; }
  else if (id < 5120) { int t = id - 4096; in = Wk; out = WTa + (size_t)2048 * 2048; is = 512; os = 2048; bx = t & 15; by = t >> 4; }
  else if (id < 6144) { int t = id - 5120; in = Wv; out = WTa + (size_t)2560 * 2048; is = 512; os = 2048; bx = t & 15; by = t >> 4; }
  else                { int t = id - 6144; in = Wp; out = WpT;       is = 2048; os = 2048; bx = t & 63; by = t >> 6; }
  int c0 = bx * 32, r0 = by * 32;
#pragma unroll
  for (int i = 0; i < 32; i += 8)
    tile[ty + i][tx] = in[(size_t)(r0 + ty + i) * is + c0 + tx];
  __syncthreads();
#pragma unroll
  for (int i = 0; i < 32; i += 8)
    out[(size_t)(c0 + ty + i) * os + r0 + tx] = __float2bfloat16(tile[tx][ty + i]);
}

// ---------------- qkv GEMM: 128x128 tile, BK=64, 4 waves, 2-phase counted-vmcnt ----------------
__global__ __launch_bounds__(256, 2) void gemm_qkv_rope_kernel(
    const __hip_bfloat16* __restrict__ A,
    const __hip_bfloat16* __restrict__ Bt,
    const float* __restrict__ cosb,
    const float* __restrict__ sinb,
    __hip_bfloat16* __restrict__ qT,
    __hip_bfloat16* __restrict__ kT,
    __hip_bfloat16* __restrict__ vt) {
  __shared__ __align__(16) char smem[65536];
  __hip_bfloat16* CL4 = (__hip_bfloat16*)smem;    // elem idx = (q4*133+col)*4 + rr
  const int K = 2048;
  const int tid = threadIdx.x;
  const int lane = tid & 63;
  const int wid = tid >> 6;
  const int wm = wid >> 1, wn = wid & 1;
  const int bid = blockIdx.x;
  const int swz = (bid & 7) * 96 + (bid >> 3);
  const int tm = swz / 24, tn = swz % 24;
  const int row0 = tm << 7, col0 = tn << 7;
  const int fr = lane & 15, hi = lane >> 4;

  auto STAGE = [&](int buf, int k0) {
#pragma unroll
    for (int i = 0; i < 4; ++i) {
      int f = i * 256 + tid;
      int r = f >> 3, s = f & 7, sx = s ^ (r & 7);
      gload_lds16(A + (size_t)(row0 + r) * K + k0 + sx * 8,
                  smem + buf * 16384 + f * 16);
    }
#pragma unroll
    for (int i = 0; i < 4; ++i) {
      int f = i * 256 + tid;
      int r = f >> 3, s = f & 7, sx = s ^ (r & 7);
      gload_lds16(Bt + (size_t)(col0 + r) * K + k0 + sx * 8,
                  smem + 32768 + buf * 16384 + f * 16);
    }
  };

  f32x4 acc[4][4] = {};
  STAGE(0, 0);
  int cur = 0;
  for (int kk = 0; kk < 32; ++kk) {
    if (kk > 0) __builtin_amdgcn_s_barrier();
    __builtin_amdgcn_sched_barrier(0);
    if (kk + 1 < 32) STAGE(cur ^ 1, (kk + 1) * 64);
    __builtin_amdgcn_sched_barrier(0);
    if (kk + 1 < 32) asm volatile("s_waitcnt vmcnt(8)" ::: "memory");
    else             asm volatile("s_waitcnt vmcnt(0)" ::: "memory");
    __builtin_amdgcn_s_barrier();
    __builtin_amdgcn_sched_barrier(0);
    const char* Ac = smem + cur * 16384;
    const char* Bc = smem + 32768 + cur * 16384;
#pragma unroll
    for (int kh = 0; kh < 2; ++kh) {
      bf16x8 af[4], bfr[4];
#pragma unroll
      for (int n = 0; n < 4; ++n) {
        int rowb = wn * 64 + n * 16 + fr;
        int sl = (kh * 4 + hi) ^ (rowb & 7);
        bfr[n] = *(const bf16x8*)(Bc + rowb * 128 + sl * 16);
      }
#pragma unroll
      for (int m = 0; m < 4; ++m) {
        int rowa = wm * 64 + m * 16 + fr;
        int sl = (kh * 4 + hi) ^ (rowa & 7);
        af[m] = *(const bf16x8*)(Ac + rowa * 128 + sl * 16);
      }
      __builtin_amdgcn_s_setprio(1);
#pragma unroll
      for (int m = 0; m < 4; ++m)
#pragma unroll
        for (int n = 0; n < 4; ++n)
          acc[m][n] = MFMA_BF16(af[m], bfr[n], acc[m][n]);
      __builtin_amdgcn_s_setprio(0);
    }
    cur ^= 1;
  }
  __syncthreads();

  // ---- pack acc -> CL4 ----
#pragma unroll
  for (int m = 0; m < 4; ++m)
#pragma unroll
    for (int n = 0; n < 4; ++n) {
      int q4 = wm * 16 + m * 4 + hi;
      int col = wn * 64 + n * 16 + fr;
      *(uint2*)(CL4 + ((q4 * 133 + col) << 2)) =
          make_uint2(pk2(acc[m][n][0], acc[m][n][1]), pk2(acc[m][n][2], acc[m][n][3]));
    }
  __syncthreads();

  const int b = row0 >> 11;
  const int t0 = row0 & 2047;

  if (col0 >= 2560) {
    const int hv = (col0 - 2560) >> 7;
    __hip_bfloat16* vb = vt + (size_t)(b * 4 + hv) * 128 * 2048;
    const int col = tid >> 1, th = tid & 1;
    uint2 w[16];
#pragma unroll
    for (int qq = 0; qq < 16; ++qq)
      w[qq] = *(const uint2*)(CL4 + (((th * 16 + qq) * 133 + col) << 2));
    __hip_bfloat16* dstv = vb + (size_t)col * 2048 + t0 + th * 64;
#pragma unroll
    for (int e = 0; e < 8; ++e)
      *(uint4*)(dstv + e * 8) = make_uint4(w[2 * e].x, w[2 * e].y, w[2 * e + 1].x, w[2 * e + 1].y);
    return;
  }

  const int quad = tid >> 3, cp = tid & 7;
  const int tb = t0 + quad * 4;
  bf16x8 lov[4], hiv[4];
#pragma unroll
  for (int e = 0; e < 4; ++e) {
    lov[e] = *(const bf16x8*)(CL4 + ((quad * 133 + cp * 8 + e * 2) << 2));
    hiv[e] = *(const bf16x8*)(CL4 + ((quad * 133 + 64 + cp * 8 + e * 2) << 2));
  }
  const float oscale = (col0 < 2048) ? QSCALE : 1.0f;
  __hip_bfloat16* dstq = (col0 < 2048)
      ? qT + (size_t)(b * 16 + (col0 >> 7)) * 2048 * 128
      : kT + (size_t)(b * 4 + ((col0 - 2048) >> 7)) * 2048 * 128;

  float o1v[4][8], o2v[4][8], ssum[4];
#pragma unroll
  for (int rr = 0; rr < 4; ++rr) {
    const float* cb = cosb + (size_t)(tb + rr) * 64 + cp * 8;
    const float* sb = sinb + (size_t)(tb + rr) * 64 + cp * 8;
    float4 c0 = *(const float4*)cb, c1 = *(const float4*)(cb + 4);
    float4 s0 = *(const float4*)sb, s1 = *(const float4*)(sb + 4);
    float cc[8] = {c0.x, c0.y, c0.z, c0.w, c1.x, c1.y, c1.z, c1.w};
    float sn[8] = {s0.x, s0.y, s0.z, s0.w, s1.x, s1.y, s1.z, s1.w};
    float ss = 0.f;
#pragma unroll
    for (int e = 0; e < 4; ++e)
#pragma unroll
      for (int w2 = 0; w2 < 2; ++w2) {
        int pd = e * 2 + w2;
        float x1 = b2f((unsigned short)lov[e][w2 * 4 + rr]);
        float x2 = b2f((unsigned short)hiv[e][w2 * 4 + rr]);
        float a = x1 * cc[pd] - x2 * sn[pd];
        float bb = x1 * sn[pd] + x2 * cc[pd];
        o1v[rr][pd] = a;
        o2v[rr][pd] = bb;
        ss += a * a + bb * bb;
      }
    ssum[rr] = ss;
  }
#pragma unroll
  for (int rr = 0; rr < 4; ++rr) {
    float rn = rsqrtf(red8_sum(ssum[rr]) * (1.f / 128.f) + 1e-6f) * oscale;
    __hip_bfloat16* dr = dstq + (size_t)(tb + rr) * 128 + cp * 8;
    *(uint4*)dr = make_uint4(pk2(o1v[rr][0] * rn, o1v[rr][1] * rn),
                             pk2(o1v[rr][2] * rn, o1v[rr][3] * rn),
                             pk2(o1v[rr][4] * rn, o1v[rr][5] * rn),
                             pk2(o1v[rr][6] * rn, o1v[rr][7] * rn));
    *(uint4*)(dr + 64) = make_uint4(pk2(o2v[rr][0] * rn, o2v[rr][1] * rn),
                                    pk2(o2v[rr][2] * rn, o2v[rr][3] * rn),
                                    pk2(o2v[rr][4] * rn, o2v[rr][5] * rn),
                                    pk2(o2v[rr][6] * rn, o2v[rr][7] * rn));
  }
}

// ---------------- generic bf16 GEMM: 128x128 tile, BK=64, swizzled (f32 out) ----------------
__global__ __launch_bounds__(256, 2) void gemm_bf16_kernel(const __hip_bfloat16* __restrict__ A,
                                                           const __hip_bfloat16* __restrict__ Bt,
                                                           float* __restrict__ C,
                                                           int M, int N, int K) {
  __shared__ __align__(16) char smem[65536];
  const int tid = threadIdx.x;
  const int lane = tid & 63;
  const int wid = tid >> 6;
  const int wm = wid >> 1, wn = wid & 1;
  const int nwg = gridDim.x;
  const int bid = blockIdx.x;
  const int swz = (bid & 7) * (nwg >> 3) + (bid >> 3);
  const int ntile = N >> 7;
  const int tm = swz / ntile, tn = swz % ntile;
  const int row0 = tm << 7, col0 = tn << 7;
  const int fr = lane & 15, hi = lane >> 4;

  auto STAGE = [&](int buf, int k0) {
#pragma unroll
    for (int i = 0; i < 4; ++i) {
      int f = i * 256 + tid;
      int r = f >> 3, s = f & 7, sx = s ^ (r & 7);
      gload_lds16(A + (size_t)(row0 + r) * K + k0 + sx * 8,
                  smem + buf * 16384 + f * 16);
    }
#pragma unroll
    for (int i = 0; i < 4; ++i) {
      int f = i * 256 + tid;
      int r = f >> 3, s = f & 7, sx = s ^ (r & 7);
      gload_lds16(Bt + (size_t)(col0 + r) * K + k0 + sx * 8,
                  smem + 32768 + buf * 16384 + f * 16);
    }
  };

  f32x4 acc[4][4] = {};
  const int nk = K >> 6;
  STAGE(0, 0);
  int cur = 0;
  for (int kk = 0; kk < nk; ++kk) {
    if (kk > 0) __builtin_amdgcn_s_barrier();
    __builtin_amdgcn_sched_barrier(0);
    if (kk + 1 < nk) STAGE(cur ^ 1, (kk + 1) * 64);
    __builtin_amdgcn_sched_barrier(0);
    if (kk + 1 < nk) asm volatile("s_waitcnt vmcnt(8)" ::: "memory");
    else             asm volatile("s_waitcnt vmcnt(0)" ::: "memory");
    __builtin_amdgcn_s_barrier();
    __builtin_amdgcn_sched_barrier(0);
    const char* Ac = smem + cur * 16384;
    const char* Bc = smem + 32768 + cur * 16384;
#pragma unroll
    for (int kh = 0; kh < 2; ++kh) {
      bf16x8 af[4], bfr[4];
#pragma unroll
      for (int n = 0; n < 4; ++n) {
        int rowb = wn * 64 + n * 16 + fr;
        int sl = (kh * 4 + hi) ^ (rowb & 7);
        bfr[n] = *(const bf16x8*)(Bc + rowb * 128 + sl * 16);
      }
#pragma unroll
      for (int m = 0; m < 4; ++m) {
        int rowa = wm * 64 + m * 16 + fr;
        int sl = (kh * 4 + hi) ^ (rowa & 7);
        af[m] = *(const bf16x8*)(Ac + rowa * 128 + sl * 16);
      }
      __builtin_amdgcn_s_setprio(1);
#pragma unroll
      for (int m = 0; m < 4; ++m)
#pragma unroll
        for (int n = 0; n < 4; ++n)
          acc[m][n] = MFMA_BF16(af[m], bfr[n], acc[m][n]);
      __builtin_amdgcn_s_setprio(0);
    }
    cur ^= 1;
  }

  const int cr = hi * 4;
#pragma unroll
  for (int m = 0; m < 4; ++m)
#pragma unroll
    for (int n = 0; n < 4; ++n) {
      int col = col0 + wn * 64 + n * 16 + fr;
#pragma unroll
      for (int r = 0; r < 4; ++r) {
        int row = row0 + wm * 64 + m * 16 + cr + r;
        C[(size_t)row * N + col] = acc[m][n][r];
      }
    }
}

// block decode (both passes): bi in [0,512): u=bi&255, half=bi>>8. g=u&7 = (b*4+kvh).
// bi and bi+256 (two halves of a balanced 34-step pair) land on the same CU under rr
// dispatch: per-CU balance at 2 blocks/CU.
//
// STATIC-MAX SOFTMAX: no online max tracking (scores bounded by SMAX); P = exp2(s-SMAX),
// l accumulated per-lane, reduced once in the epilogue. Zero cross-lane ops in the loop.
// QK-AHEAD pipeline (both passes): iter s computes QK(s+1) into sfN while
// exp2/pack/PV(s) run on sfC. K staged two-ahead, V one-ahead, counted vmcnt(8/4/0).

// ---------------- attention pass 1: y1 = softmax(qk^T) v ; writes u = mix1*v + mix2*y1 ----------------
__global__ __launch_bounds__(256, 2) void attn_pass1_kernel(
    const __hip_bfloat16* __restrict__ qT,   // (B,H,T,HD), q pre-scaled
    const __hip_bfloat16* __restrict__ kT,   // (B,HK,T,HD)
    const __hip_bfloat16* __restrict__ vt,   // (B,HK,HD,T)
    __hip_bfloat16* __restrict__ y1u,        // (B,H,HD,T)  u = mix1*v + mix2*y1
    float* __restrict__ Lb,                  // (B,H,T)
    const float* __restrict__ mix1p,
    const float* __restrict__ mix2p) {
  __shared__ __align__(16) __hip_bfloat16 Ks[2][64 * 128];
  __shared__ __align__(16) __hip_bfloat16 Vs[2][128 * 64];
  __shared__ __align__(16) char Ps[4][32 * 128];
  const int tid = threadIdx.x, lane = tid & 63, wid = tid >> 6;   // wid 0..3
  const int bi = blockIdx.x;
  const int u = bi & 255, half = bi >> 8;
  const int g = u & 7;
  const int pslot = (u >> 3) & 7;
  const int bh = g * 4 + (u >> 6);
  const int j = half ? (15 - pslot) : pslot;
  const int q0 = j * 128;
  const int nt = 2 * j + 2;                  // even
  const int sd = 2 * j + (wid >> 1);
  const __hip_bfloat16* Kp = kT + (size_t)g * 2048 * 128;
  const __hip_bfloat16* Vp = vt + (size_t)g * 128 * 2048;
  const int fr = lane & 15, hi = lane >> 4;

  bf16x8 qf[2][4];
  {
    const __hip_bfloat16* Qp = qT + ((size_t)bh * 2048 + q0 + wid * 32) * 128;
#pragma unroll
    for (int rr = 0; rr < 2; ++rr)
#pragma unroll
      for (int dc = 0; dc < 4; ++dc)
        qf[rr][dc] = *(const bf16x8*)(Qp + (rr * 16 + fr) * 128 + dc * 32 + hi * 8);
  }

  f32x4 accO[2][8] = {};
  float l[2] = {0.f, 0.f};                   // per-lane partial denominators
  char* Pb = Ps[wid];

  auto STAGE_K = [&](int buf, int kt) {      // 4 loads/thread
    const int k0 = kt * 64;
#pragma unroll
    for (int i = 0; i < 4; ++i) {
      int f = i * 256 + tid;
      int r = f >> 4, s = f & 15, sx = s ^ (r & 7);
      gload_lds16(Kp + (size_t)(k0 + r) * 128 + sx * 8,
                  (char*)Ks[buf] + (i * 256 + wid * 64) * 16);
    }
  };
  auto STAGE_V = [&](int buf, int kt) {      // 4 loads/thread
    const int k0 = kt * 64;
#pragma unroll
    for (int i = 0; i < 4; ++i) {
      int f = i * 256 + tid;
      int r = f >> 3, s = f & 7, sx = s ^ (r & 7);
      gload_lds16(Vp + (size_t)r * 2048 + k0 + sx * 8,
                  (char*)Vs[buf] + (i * 256 + wid * 64) * 16);
    }
  };

  auto QK = [&](int t, f32x4 (&sf)[2][4]) {  // S(t) from Ks[t&1]
    const char* Kc = (const char*)Ks[t & 1];
#pragma unroll
    for (int rr = 0; rr < 2; ++rr)
#pragma unroll
      for (int c = 0; c < 4; ++c) sf[rr][c] = (f32x4){0.f, 0.f, 0.f, 0.f};
    __builtin_amdgcn_s_setprio(1);
#pragma unroll
    for (int c = 0; c < 4; ++c) {
      const int krow = c * 16 + fr;
#pragma unroll
      for (int dc = 0; dc < 4; ++dc) {
        int slot = (dc * 4 + hi) ^ (krow & 7);
        bf16x8 kf = *(const bf16x8*)(Kc + krow * 256 + slot * 16);
        sf[0][c] = MFMA_BF16(kf, qf[0][dc], sf[0][c]);
        sf[1][c] = MFMA_BF16(kf, qf[1][dc], sf[1][c]);
      }
    }
    __builtin_amdgcn_s_setprio(0);
  };

  auto STEP = [&](int s, f32x4 (&sfC)[2][4], f32x4 (&sfN)[2][4]) {
    __builtin_amdgcn_s_barrier();            // close compute(s-1)/prologue-QK
    __builtin_amdgcn_sched_barrier(0);
    if (s + 2 < nt) STAGE_K(s & 1, s + 2);
    if (s + 1 < nt) STAGE_V((s + 1) & 1, s + 1);
    __builtin_amdgcn_sched_barrier(0);
    if (s + 2 < nt)      asm volatile("s_waitcnt vmcnt(8)" ::: "memory");
    else if (s + 1 < nt) asm volatile("s_waitcnt vmcnt(4)" ::: "memory");
    else                 asm volatile("s_waitcnt vmcnt(0)" ::: "memory");
    __builtin_amdgcn_s_barrier();            // K(s+1), V(s) landed for all waves
    __builtin_amdgcn_sched_barrier(0);

    if (s + 1 <= sd) QK(s + 1, sfN);         // pipeline: next tile's scores

    if (s <= sd) {
      // ---- mask (diagonal only) + static-max exp2 + per-lane partial sum ----
      if (s == sd) {
#pragma unroll
        for (int rr = 0; rr < 2; ++rr) {
          const int qq = q0 + wid * 32 + rr * 16 + fr;
#pragma unroll
          for (int c = 0; c < 4; ++c) {
            const int kb = s * 64 + c * 16 + hi * 4;
#pragma unroll
            for (int r = 0; r < 4; ++r)
              if (kb + r > qq) sfC[rr][c][r] = -1e30f;
          }
        }
      }
#pragma unroll
      for (int rr = 0; rr < 2; ++rr) {
        float rs = 0.f;
#pragma unroll
        for (int c = 0; c < 4; ++c)
#pragma unroll
          for (int r = 0; r < 4; ++r) {
            float p = __builtin_amdgcn_exp2f(sfC[rr][c][r] - SMAX);
            sfC[rr][c][r] = p;
            rs += p;
          }
        l[rr] += rs;
      }
      // ---- P -> LDS (packed b64, swizzled) + A-frag readback ----
#pragma unroll
      for (int rr = 0; rr < 2; ++rr) {
        const int row = rr * 16 + fr;
        char* Prow = Pb + row * 128;
#pragma unroll
        for (int c = 0; c < 4; ++c) {
          uint32_t w0 = pk2(sfC[rr][c][0], sfC[rr][c][1]);
          uint32_t w1 = pk2(sfC[rr][c][2], sfC[rr][c][3]);
          int sl = (c * 2 + (hi >> 1)) ^ (row & 7);
          *(uint2*)(Prow + sl * 16 + (hi & 1) * 8) = make_uint2(w0, w1);
        }
      }
      bf16x8 pf[2][2];
#pragma unroll
      for (int rr = 0; rr < 2; ++rr) {
        const int row = rr * 16 + fr;
#pragma unroll
        for (int kc = 0; kc < 2; ++kc) {
          int sl = (kc * 4 + hi) ^ (row & 7);
          pf[rr][kc] = *(const bf16x8*)(Pb + row * 128 + sl * 16);
        }
      }
      // ---- PV from Vs[s&1] ----
      const __hip_bfloat16* Vc = Vs[s & 1];
      __builtin_amdgcn_s_setprio(1);
#pragma unroll
      for (int kc = 0; kc < 2; ++kc)
#pragma unroll
        for (int f = 0; f < 8; ++f) {
          int vrow = f * 16 + fr;
          int vslot = (kc * 4 + hi) ^ (fr & 7);
          bf16x8 vf = *(const bf16x8*)(Vc + vrow * 64 + vslot * 8);
          accO[0][f] = MFMA_BF16(pf[0][kc], vf, accO[0][f]);
          accO[1][f] = MFMA_BF16(pf[1][kc], vf, accO[1][f]);
        }
      __builtin_amdgcn_s_setprio(0);
    }
  };

  // prologue: K0, V0, K1 staged; QK(0)
  f32x4 sfA[2][4], sfB[2][4];
  STAGE_K(0, 0);
  STAGE_V(0, 0);
  STAGE_K(1, 1);
  asm volatile("s_waitcnt vmcnt(8)" ::: "memory");   // K0 landed (V0, K1 in flight)
  __builtin_amdgcn_s_barrier();
  __builtin_amdgcn_sched_barrier(0);
  QK(0, sfA);

  for (int s2 = 0; s2 < nt; s2 += 2) {
    STEP(s2, sfA, sfB);
    STEP(s2 + 1, sfB, sfA);
  }

  // ---- epilogue: reduce per-lane l once; u = mix1*v + mix2*(accO/l); store l ----
  float lsum[2];
#pragma unroll
  for (int rr = 0; rr < 2; ++rr) {
    float v = l[rr];
    v += __shfl_xor(v, 16);
    v += __shfl_xor(v, 32);
    lsum[rr] = v;
  }
  const float m1v = mix1p[0], m2v = mix2p[0];
  float rlq[2][4];
#pragma unroll
  for (int rr = 0; rr < 2; ++rr) {
    float inv = 1.f / lsum[rr];
#pragma unroll
    for (int r = 0; r < 4; ++r) rlq[rr][r] = __shfl(inv, hi * 4 + r);
  }
  const int t0 = q0 + wid * 32;
#pragma unroll
  for (int rr = 0; rr < 2; ++rr) {
    const int tb = t0 + rr * 16 + hi * 4;
#pragma unroll
    for (int f = 0; f < 8; ++f) {
      const int d = f * 16 + fr;
      const ushort4 v4 = *(const ushort4*)(vt + ((size_t)g * 128 + d) * 2048 + tb);
      float u0 = m1v * b2f(v4.x) + m2v * (accO[rr][f][0] * rlq[rr][0]);
      float u1 = m1v * b2f(v4.y) + m2v * (accO[rr][f][1] * rlq[rr][1]);
      float u2 = m1v * b2f(v4.z) + m2v * (accO[rr][f][2] * rlq[rr][2]);
      float u3 = m1v * b2f(v4.w) + m2v * (accO[rr][f][3] * rlq[rr][3]);
      *(uint2*)(y1u + ((size_t)bh * 128 + d) * 2048 + tb) =
          make_uint2(pk2(u0, u1), pk2(u2, u3));
    }
  }
  if (hi == 0) {
#pragma unroll
    for (int rr = 0; rr < 2; ++rr)
      Lb[(size_t)bh * 2048 + t0 + rr * 16 + fr] = lsum[rr];
  }
}

// ---------------- attention pass 2: ymix = att @ u  (direct final output) ----------------
// QK-AHEAD pipeline; normalization DEFERRED to the epilogue.
__global__ __launch_bounds__(256, 2) void attn_pass2_kernel(
    const __hip_bfloat16* __restrict__ qT,
    const __hip_bfloat16* __restrict__ kT,
    const __hip_bfloat16* __restrict__ y1u,  // (B,H,HD,T)
    const float* __restrict__ Lb,
    __hip_bfloat16* __restrict__ ymix) {     // (B,T,C)
  __shared__ __align__(16) __hip_bfloat16 Ks[2][64 * 128];
  __shared__ __align__(16) __hip_bfloat16 Vs[2][128 * 64];
  __shared__ __align__(16) char Ps[4][32 * 128];
  const int tid = threadIdx.x, lane = tid & 63, wid = tid >> 6;
  const int bi = blockIdx.x;
  const int u = bi & 255, half = bi >> 8;
  const int g = u & 7;
  const int pslot = (u >> 3) & 7;
  const int bh = g * 4 + (u >> 6);
  const int h = bh & 15, b = bh >> 4;
  const int j = half ? (15 - pslot) : pslot;
  const int q0 = j * 128;
  const int nt = 2 * j + 2;                  // even
  const int sd = 2 * j + (wid >> 1);
  const __hip_bfloat16* Kp = kT + (size_t)g * 2048 * 128;
  const __hip_bfloat16* Yp = y1u + (size_t)bh * 128 * 2048;
  const int fr = lane & 15, hi = lane >> 4;

  bf16x8 qf[2][4];
  float rl[2];
  {
    const __hip_bfloat16* Qp = qT + ((size_t)bh * 2048 + q0 + wid * 32) * 128;
#pragma unroll
    for (int rr = 0; rr < 2; ++rr)
#pragma unroll
      for (int dc = 0; dc < 4; ++dc)
        qf[rr][dc] = *(const bf16x8*)(Qp + (rr * 16 + fr) * 128 + dc * 32 + hi * 8);
    const size_t qb = (size_t)bh * 2048 + q0 + wid * 32;
    rl[0] = 1.f / Lb[qb + fr];
    rl[1] = 1.f / Lb[qb + 16 + fr];
  }

  f32x4 accO[2][8] = {};
  char* Pb = Ps[wid];

  auto STAGE_K = [&](int buf, int kt) {      // 4 loads/thread
    const int k0 = kt * 64;
#pragma unroll
    for (int i = 0; i < 4; ++i) {
      int f = i * 256 + tid;
      int r = f >> 4, s = f & 15, sx = s ^ (r & 7);
      gload_lds16(Kp + (size_t)(k0 + r) * 128 + sx * 8,
                  (char*)Ks[buf] + (i * 256 + wid * 64) * 16);
    }
  };
  auto STAGE_V = [&](int buf, int kt) {      // 4 loads/thread
    const int k0 = kt * 64;
#pragma unroll
    for (int i = 0; i < 4; ++i) {
      int f = i * 256 + tid;
      int r = f >> 3, s = f & 7, sx = s ^ (r & 7);
      gload_lds16(Yp + (size_t)r * 2048 + k0 + sx * 8,
                  (char*)Vs[buf] + (i * 256 + wid * 64) * 16);
    }
  };

  auto QK = [&](int t, f32x4 (&sf)[2][4]) {  // S(t) from Ks[t&1]
    const char* Kc = (const char*)Ks[t & 1];
#pragma unroll
    for (int rr = 0; rr < 2; ++rr)
#pragma unroll
      for (int c = 0; c < 4; ++c) sf[rr][c] = (f32x4){0.f, 0.f, 0.f, 0.f};
    __builtin_amdgcn_s_setprio(1);
#pragma unroll
    for (int c = 0; c < 4; ++c) {
      const int krow = c * 16 + fr;
#pragma unroll
      for (int dc = 0; dc < 4; ++dc) {
        int slot = (dc * 4 + hi) ^ (krow & 7);
        bf16x8 kf = *(const bf16x8*)(Kc + krow * 256 + slot * 16);
        sf[0][c] = MFMA_BF16(kf, qf[0][dc], sf[0][c]);
        sf[1][c] = MFMA_BF16(kf, qf[1][dc], sf[1][c]);
      }
    }
    __builtin_amdgcn_s_setprio(0);
  };

  auto STEP = [&](int s, f32x4 (&sfC)[2][4], f32x4 (&sfN)[2][4]) {
    __builtin_amdgcn_s_barrier();            // close compute(s-1)/prologue-QK
    __builtin_amdgcn_sched_barrier(0);
    if (s + 2 < nt) STAGE_K(s & 1, s + 2);
    if (s + 1 < nt) STAGE_V((s + 1) & 1, s + 1);
    __builtin_amdgcn_sched_barrier(0);
    if (s + 2 < nt)      asm volatile("s_waitcnt vmcnt(8)" ::: "memory");
    else if (s + 1 < nt) asm volatile("s_waitcnt vmcnt(4)" ::: "memory");
    else                 asm volatile("s_waitcnt vmcnt(0)" ::: "memory");
    __builtin_amdgcn_s_barrier();            // K(s+1), V(s) landed for all waves
    __builtin_amdgcn_sched_barrier(0);

    if (s + 1 <= sd) QK(s + 1, sfN);         // pipeline: next tile's scores

    if (s <= sd) {
      // ---- mask (diagonal only) + static-max exp2 (UNNORMALIZED) ----
      if (s == sd) {
#pragma unroll
        for (int rr = 0; rr < 2; ++rr) {
          const int qq = q0 + wid * 32 + rr * 16 + fr;
#pragma unroll
          for (int c = 0; c < 4; ++c) {
            const int kb = s * 64 + c * 16 + hi * 4;
#pragma unroll
            for (int r = 0; r < 4; ++r)
              if (kb + r > qq) sfC[rr][c][r] = -1e30f;
          }
        }
      }
#pragma unroll
      for (int rr = 0; rr < 2; ++rr)
#pragma unroll
        for (int c = 0; c < 4; ++c)
#pragma unroll
          for (int r = 0; r < 4; ++r)
            sfC[rr][c][r] = __builtin_amdgcn_exp2f(sfC[rr][c][r] - SMAX);
      // ---- P -> LDS (packed b64, swizzled) + A-frag readback ----
#pragma unroll
      for (int rr = 0; rr < 2; ++rr) {
        const int row = rr * 16 + fr;
        char* Prow = Pb + row * 128;
#pragma unroll
        for (int c = 0; c < 4; ++c) {
          uint32_t w0 = pk2(sfC[rr][c][0], sfC[rr][c][1]);
          uint32_t w1 = pk2(sfC[rr][c][2], sfC[rr][c][3]);
          int sl = (c * 2 + (hi >> 1)) ^ (row & 7);
          *(uint2*)(Prow + sl * 16 + (hi & 1) * 8) = make_uint2(w0, w1);
        }
      }
      bf16x8 pf[2][2];
#pragma unroll
      for (int rr = 0; rr < 2; ++rr) {
        const int row = rr * 16 + fr;
#pragma unroll
        for (int kc = 0; kc < 2; ++kc) {
          int sl = (kc * 4 + hi) ^ (row & 7);
          pf[rr][kc] = *(const bf16x8*)(Pb + row * 128 + sl * 16);
        }
      }
      // ---- PV from Vs[s&1] ----
      const __hip_bfloat16* Vc = Vs[s & 1];
      __builtin_amdgcn_s_setprio(1);
#pragma unroll
      for (int kc = 0; kc < 2; ++kc)
#pragma unroll
        for (int f = 0; f < 8; ++f) {
          int vrow = f * 16 + fr;
          int vslot = (kc * 4 + hi) ^ (fr & 7);
          bf16x8 vf = *(const bf16x8*)(Vc + vrow * 64 + vslot * 8);
          accO[0][f] = MFMA_BF16(pf[0][kc], vf, accO[0][f]);
          accO[1][f] = MFMA_BF16(pf[1][kc], vf, accO[1][f]);
        }
      __builtin_amdgcn_s_setprio(0);
    }
  };

  // prologue: K0, V0, K1 staged; QK(0)
  f32x4 sfA[2][4], sfB[2][4];
  STAGE_K(0, 0);
  STAGE_V(0, 0);
  STAGE_K(1, 1);
  asm volatile("s_waitcnt vmcnt(8)" ::: "memory");   // K0 landed (V0, K1 in flight)
  __builtin_amdgcn_s_barrier();
  __builtin_amdgcn_sched_barrier(0);
  QK(0, sfA);

  for (int s2 = 0; s2 < nt; s2 += 2) {
    STEP(s2, sfA, sfB);
    STEP(s2 + 1, sfB, sfA);
  }

  // ---- epilogue: normalize per q-row once (rlq via shuffle), write final output ----
  float rlq[2][4];
#pragma unroll
  for (int rr = 0; rr < 2; ++rr)
#pragma unroll
    for (int r = 0; r < 4; ++r) rlq[rr][r] = __shfl(rl[rr], hi * 4 + r);
#pragma unroll
  for (int rr = 0; rr < 2; ++rr) {
#pragma unroll
    for (int f = 0; f < 8; ++f) {
      const int d = f * 16 + fr;
#pragma unroll
      for (int r = 0; r < 4; ++r) {
        int q = q0 + wid * 32 + rr * 16 + hi * 4 + r;
        ymix[((size_t)b * 2048 + q) * 2048 + h * 128 + d] =
            __float2bfloat16(accO[rr][f][r] * rlq[rr][r]);
      }
    }
  }
}

// ---------------- launch ----------------
extern "C" void kernel_launch(void* const* d_in, const int* in_sizes, int n_in,
                              void* d_out, int out_size, void* d_ws, size_t ws_size,
                              hipStream_t stream) {
  const float* x    = (const float*)d_in[0];
  const float* cosb = (const float*)d_in[1];
  const float* sinb = (const float*)d_in[2];
  const float* Wq   = (const float*)d_in[3];
  const float* Wk   = (const float*)d_in[4];
  const float* Wv   = (const float*)d_in[5];
  const float* Wp   = (const float*)d_in[6];
  const float* mix1 = (const float*)d_in[7];
  const float* mix2 = (const float*)d_in[8];
  float* out = (float*)d_out;
  char* ws = (char*)d_ws;

  // workspace layout (bytes), peak ~80 MB
  __hip_bfloat16* xb   = (__hip_bfloat16*)(ws + 0);            // 16.78 MB; reused as ymix
  __hip_bfloat16* WTa  = (__hip_bfloat16*)(ws + 16777216);     // 12.58 MB
  __hip_bfloat16* WpT  = (__hip_bfloat16*)(ws + 29360128);     // 8.39 MB
  __hip_bfloat16* y1u  = (__hip_bfloat16*)(ws + 37748736);     // 16.78 MB
  float*          Lb   = (float*)(ws + 54525952);              // 0.26 MB
  __hip_bfloat16* qTb  = (__hip_bfloat16*)(ws + 55050240);     // 16.78 MB
  __hip_bfloat16* kTb  = (__hip_bfloat16*)(ws + 71827456);     // 4.19 MB
  __hip_bfloat16* vtb  = (__hip_bfloat16*)(ws + 76021760);     // 4.19 MB
  __hip_bfloat16* ymix = (__hip_bfloat16*)(ws + 0);

  dim3 tb(32, 8);
  prep_kernel<<<18432, tb, 0, stream>>>(x, xb, Wq, Wk, Wv, Wp, WTa, WpT);

  // fused QKV projection + RoPE + RMS + V-transpose (128x128 tiles, BK=64, 768 blocks)
  gemm_qkv_rope_kernel<<<768, 256, 0, stream>>>(xb, WTa, cosb, sinb, qTb, kTb, vtb);

  attn_pass1_kernel<<<512, 256, 0, stream>>>(qTb, kTb, vtb, y1u, Lb, mix1, mix2);
  attn_pass2_kernel<<<512, 256, 0, stream>>>(qTb, kTb, y1u, Lb, ymix);

  gemm_bf16_kernel<<<512, 256, 0, stream>>>(ymix, WpT, out, 4096, 2048, 2048);
}